// Round 3
// baseline (523.028 us; speedup 1.0000x reference)
//
#include <hip/hip_runtime.h>
#include <math.h>

// Problem constants
#define Bn 2
#define Sn 512
#define Hn 128
#define NHn 4
#define Dn 32
#define BAGn 5
#define NMETAn 16
#define ROWS 1024
#define NBn 2
#define Tt 257

#define NEGF (-4294967295.0f)
#define INV_SQRT_D 0.17677669529663687f
#define SQRT_H 11.313708498984761f
#define EPS_EMB 1e-5f
#define EPSF 1e-8f

// workspace float offsets
#define OFF_VECS  0
#define OFF_QN    131072
#define OFF_Q     262144
#define OFF_K     393216
#define OFF_V     524288
#define OFF_O     655360
#define OFF_QT    786432          // 8*512*257 = 1052672 floats
#define OFF_TKT   1839104         // 128*257 = 32896
#define OFF_FUSWT 1872000         // 256*128
#define OFF_QWT   1904768         // 2*16384
#define OFF_KWT   1937536
#define OFF_VWT   1970304
#define OFF_W1WT  2003072
#define OFF_W2WT  2035840

static __device__ __forceinline__ float red64(float v) {
#pragma unroll
    for (int m = 1; m < 64; m <<= 1) v += __shfl_xor(v, m, 64);
    return v;
}
static __device__ __forceinline__ float red32sum(float v) {
#pragma unroll
    for (int m = 1; m < 32; m <<= 1) v += __shfl_xor(v, m, 32);
    return v;
}
static __device__ __forceinline__ float red32max(float v) {
#pragma unroll
    for (int m = 1; m < 32; m <<= 1) v = fmaxf(v, __shfl_xor(v, m, 32));
    return v;
}

// ---------------------------------------------------------------------------
// Transpose all weight matrices into ws (once per call).
// blocks 0..31: fusW [128,256] -> fusWT [256,128]
// blocks 32..191: 10 x [128,128] (QW0,QW1,KW0,KW1,VW0,VW1,w1W0,w1W1,w2W0,w2W1)
// blocks 192..227: tKw [257,128] -> tKT [128,257]
// ---------------------------------------------------------------------------
__global__ __launch_bounds__(256) void transpose_all(
    const float* __restrict__ fusW, const float* __restrict__ QW,
    const float* __restrict__ KW, const float* __restrict__ VW,
    const float* __restrict__ w1W, const float* __restrict__ w2W,
    const float* __restrict__ tKw, float* __restrict__ ws)
{
    int bid = blockIdx.x;
    const float* src; float* dst; int R, C, tile;
    if (bid < 32) { src = fusW; dst = ws + OFF_FUSWT; R = 128; C = 256; tile = bid; }
    else if (bid < 192) {
        int m = (bid - 32) >> 4; tile = (bid - 32) & 15; R = 128; C = 128;
        switch (m) {
            case 0: src = QW;          dst = ws + OFF_QWT;          break;
            case 1: src = QW + 16384;  dst = ws + OFF_QWT + 16384;  break;
            case 2: src = KW;          dst = ws + OFF_KWT;          break;
            case 3: src = KW + 16384;  dst = ws + OFF_KWT + 16384;  break;
            case 4: src = VW;          dst = ws + OFF_VWT;          break;
            case 5: src = VW + 16384;  dst = ws + OFF_VWT + 16384;  break;
            case 6: src = w1W;         dst = ws + OFF_W1WT;         break;
            case 7: src = w1W + 16384; dst = ws + OFF_W1WT + 16384; break;
            case 8: src = w2W;         dst = ws + OFF_W2WT;         break;
            default:src = w2W + 16384; dst = ws + OFF_W2WT + 16384; break;
        }
    } else { src = tKw; dst = ws + OFF_TKT; R = 257; C = 128; tile = bid - 192; }

    int ctiles = C >> 5;
    int rt = tile / ctiles, ct = tile % ctiles;
    int r0 = rt * 32, c0 = ct * 32;
    __shared__ float ts[32][33];
    int c = threadIdx.x & 31, r = threadIdx.x >> 5;
#pragma unroll
    for (int rr = r; rr < 32; rr += 8) {
        int gr = r0 + rr;
        ts[rr][c] = (gr < R) ? src[gr * C + c0 + c] : 0.f;
    }
    __syncthreads();
    int rr2 = threadIdx.x & 31, cb = threadIdx.x >> 5;
#pragma unroll
    for (int cc = cb; cc < 32; cc += 8) {
        int gr = r0 + rr2;
        if (gr < R) dst[(c0 + cc) * R + gr] = ts[rr2][cc];
    }
}

// ---------------------------------------------------------------------------
// Embed: item/cat/num -> fusion GEMM (transposed W) -> LN -> keep.
// 4 rows per block, 256 threads.
// ---------------------------------------------------------------------------
__global__ __launch_bounds__(256) void embed_kernel(
    const int* __restrict__ ids, const float* __restrict__ meta,
    const int* __restrict__ cats,
    const float* __restrict__ item_w, const float* __restrict__ cat_w,
    const float* __restrict__ numW, const float* __restrict__ numb,
    const float* __restrict__ fusWT, const float* __restrict__ fusb,
    const float* __restrict__ lng, const float* __restrict__ lnb,
    float* __restrict__ vecs)
{
    int r0 = blockIdx.x * 4, t = threadIdx.x;
    __shared__ float combs[4 * 256];
    __shared__ float os[4 * 128];
    __shared__ float parts[4 * 128];
    __shared__ float mv[8];
    __shared__ int idl[4];
    if (t < 4) idl[t] = ids[r0 + t];
    __syncthreads();
    {   // item part
        int f = t, r = f >> 7, c = f & 127;
        combs[r * 256 + c] = item_w[idl[r] * Hn + c] * SQRT_H;
        f = t + 256; r = f >> 7; c = f & 127;
        combs[r * 256 + c] = item_w[idl[r] * Hn + c] * SQRT_H;
    }
    {   // num + cat parts: r = t>>6, c = t&63
        int r = t >> 6, c = t & 63;
        float acc = numb[c];
#pragma unroll
        for (int m2 = 0; m2 < NMETAn; ++m2)
            acc += meta[(r0 + r) * NMETAn + m2] * numW[c * NMETAn + m2];
        combs[r * 256 + 128 + c] = acc;
        float ca = 0.f; int cnt = 0;
#pragma unroll
        for (int k2 = 0; k2 < BAGn; ++k2) {
            int cc2 = cats[(r0 + r) * BAGn + k2];
            if (cc2 != 0) { ca += cat_w[cc2 * 64 + c]; cnt++; }
        }
        combs[r * 256 + 192 + c] = ca / (float)(cnt > 0 ? cnt : 1);
    }
    __syncthreads();
    int h = t & 127, kh = t >> 7;
    float acc[4] = {0.f, 0.f, 0.f, 0.f};
    for (int k = kh * 128; k < kh * 128 + 128; ++k) {
        float w = fusWT[k * 128 + h];
#pragma unroll
        for (int r = 0; r < 4; ++r) acc[r] += combs[r * 256 + k] * w;
    }
    if (kh) {
#pragma unroll
        for (int r = 0; r < 4; ++r) parts[r * 128 + h] = acc[r];
    }
    __syncthreads();
    if (!kh) {
#pragma unroll
        for (int r = 0; r < 4; ++r)
            os[r * 128 + h] = acc[r] + parts[r * 128 + h] + fusb[h];
    }
    __syncthreads();
    int g = t >> 6, l = t & 63;
    float a = os[g * 128 + l], b2 = os[g * 128 + 64 + l];
    float mean = red64(a + b2) * (1.f / 128.f);
    float d1 = a - mean, d2 = b2 - mean;
    float var = red64(d1 * d1 + d2 * d2) * (1.f / 128.f);
    if (l == 0) { mv[g * 2] = mean; mv[g * 2 + 1] = rsqrtf(var + EPS_EMB); }
    __syncthreads();
    {
        int f = t, r = f >> 7, c = f & 127;
        float y = (os[r * 128 + c] - mv[r * 2]) * mv[r * 2 + 1] * lng[c] + lnb[c];
        vecs[(r0 + r) * 128 + c] = (idl[r] == 0) ? 0.f : y;
        f = t + 256; r = f >> 7; c = f & 127;
        y = (os[r * 128 + c] - mv[r * 2]) * mv[r * 2 + 1] * lng[c] + lnb[c];
        vecs[(r0 + r) * 128 + c] = (idl[r] == 0) ? 0.f : y;
    }
}

// ---------------------------------------------------------------------------
// QKV: LN -> 3 GEMMs with transposed weights, posK/posV + bias folded.
// 4 rows per block, 256 threads (split-k = 2).
// ---------------------------------------------------------------------------
__global__ __launch_bounds__(256) void qkv_kernel(
    const float* __restrict__ vecs,
    const float* __restrict__ alng, const float* __restrict__ alnb,
    const float* __restrict__ QWT, const float* __restrict__ Qb,
    const float* __restrict__ KWT, const float* __restrict__ Kb,
    const float* __restrict__ VWT, const float* __restrict__ Vb,
    const float* __restrict__ posK, const float* __restrict__ posV,
    float* __restrict__ Qn, float* __restrict__ Q,
    float* __restrict__ K, float* __restrict__ V, int nb)
{
    int r0 = blockIdx.x * 4, t = threadIdx.x;
    __shared__ float xs[512], qs[512], mv[8];
    __shared__ float pq[512], pk[512], pv[512];
    {
        int f = t, r = f >> 7, c = f & 127;
        xs[r * 128 + c] = vecs[(r0 + r) * 128 + c];
        f = t + 256; r = f >> 7; c = f & 127;
        xs[r * 128 + c] = vecs[(r0 + r) * 128 + c];
    }
    __syncthreads();
    int g = t >> 6, l = t & 63;
    float a = xs[g * 128 + l], b2 = xs[g * 128 + 64 + l];
    float mean = red64(a + b2) * (1.f / 128.f);
    float d1 = a - mean, d2 = b2 - mean;
    float var = red64(d1 * d1 + d2 * d2) * (1.f / 128.f);
    if (l == 0) { mv[g * 2] = mean; mv[g * 2 + 1] = rsqrtf(var + EPSF); }
    __syncthreads();
    {
        int f = t, r = f >> 7, c = f & 127;
        float qn = (xs[r * 128 + c] - mv[r * 2]) * mv[r * 2 + 1] * alng[nb * 128 + c] + alnb[nb * 128 + c];
        qs[r * 128 + c] = qn; Qn[(r0 + r) * 128 + c] = qn;
        f = t + 256; r = f >> 7; c = f & 127;
        qn = (xs[r * 128 + c] - mv[r * 2]) * mv[r * 2 + 1] * alng[nb * 128 + c] + alnb[nb * 128 + c];
        qs[r * 128 + c] = qn; Qn[(r0 + r) * 128 + c] = qn;
    }
    __syncthreads();
    int h = t & 127, kh = t >> 7;
    float aq[4] = {0.f,0.f,0.f,0.f}, ak[4] = {0.f,0.f,0.f,0.f}, av[4] = {0.f,0.f,0.f,0.f};
    const float* qwt = QWT + nb * 16384;
    const float* kwt = KWT + nb * 16384;
    const float* vwt = VWT + nb * 16384;
    for (int k = kh * 64; k < kh * 64 + 64; ++k) {
        float wq = qwt[k * 128 + h], wk = kwt[k * 128 + h], wv = vwt[k * 128 + h];
#pragma unroll
        for (int r = 0; r < 4; ++r) {
            float qv = qs[r * 128 + k], xv = xs[r * 128 + k];
            aq[r] += qv * wq; ak[r] += xv * wk; av[r] += xv * wv;
        }
    }
    if (kh) {
#pragma unroll
        for (int r = 0; r < 4; ++r) {
            pq[r * 128 + h] = aq[r]; pk[r * 128 + h] = ak[r]; pv[r * 128 + h] = av[r];
        }
    }
    __syncthreads();
    if (!kh) {
#pragma unroll
        for (int r = 0; r < 4; ++r) {
            int row = r0 + r, s = row & (Sn - 1);
            Q[row * 128 + h] = aq[r] + pq[r * 128 + h] + Qb[nb * 128 + h];
            K[row * 128 + h] = ak[r] + pk[r * 128 + h] + Kb[nb * 128 + h] + posK[s * 128 + h];
            V[row * 128 + h] = av[r] + pv[r * 128 + h] + Vb[nb * 128 + h] + posV[s * 128 + h];
        }
    }
}

// ---------------------------------------------------------------------------
// QT precompute: QT[bh,i,t] = sum_d Q[b,i,h*32+d] * timeK[t, h*32+d]
// block = (bh, 16-i tile); thread = t-column (0..255; thread<16 handles t=256)
// ---------------------------------------------------------------------------
__global__ __launch_bounds__(256) void qt_kernel(
    const float* __restrict__ Q, const float* __restrict__ tKT,
    float* __restrict__ QT)
{
    int blk = blockIdx.x, t = threadIdx.x;
    int bh = blk >> 5, itile = blk & 31, i0 = itile * 16;
    int b = bh >> 2, h = bh & 3;
    __shared__ float Qs[16 * 33];
    {
        int f = t, i = f >> 5, d = f & 31;
        Qs[i * 33 + d] = Q[(b * Sn + i0 + i) * Hn + h * 32 + d];
        f = t + 256; i = f >> 5; d = f & 31;
        Qs[i * 33 + d] = Q[(b * Sn + i0 + i) * Hn + h * 32 + d];
    }
    __syncthreads();
    float acc[16];
#pragma unroll
    for (int i = 0; i < 16; ++i) acc[i] = 0.f;
    for (int d = 0; d < 32; ++d) {
        float w = tKT[(h * 32 + d) * Tt + t];
#pragma unroll
        for (int i = 0; i < 16; ++i) acc[i] += Qs[i * 33 + d] * w;
    }
#pragma unroll
    for (int i = 0; i < 16; ++i)
        QT[(bh * Sn + i0 + i) * Tt + t] = acc[i];
    if (t < 16) {
        int i = t; float a2 = 0.f;
        for (int d = 0; d < 32; ++d)
            a2 += Qs[i * 33 + d] * tKT[(h * 32 + d) * Tt + 256];
        QT[(bh * Sn + i0 + i) * Tt + 256] = a2;
    }
}

// ---------------------------------------------------------------------------
// Attention: block = (b,h, 8-query tile), 256 threads.
// Pass1: scores into LDS (K tiles staged, QT gather). Softmax. Pass2: PV.
// ---------------------------------------------------------------------------
__global__ __launch_bounds__(256) void attn_kernel(
    const int* __restrict__ ids, const int* __restrict__ tmat,
    const float* __restrict__ Q, const float* __restrict__ K,
    const float* __restrict__ V, const float* __restrict__ tVw,
    const float* __restrict__ QT, float* __restrict__ O)
{
    int blk = blockIdx.x, t = threadIdx.x;
    int bh = blk >> 6, itile = blk & 63, i0 = itile * 8;
    int b = bh >> 2, h = bh & 3;
    __shared__ float Qs[8 * 33];
    __shared__ float KV[64 * 33];
    __shared__ float S[8 * 512];
    __shared__ float invl[8];
    __shared__ int tlf[8];

    if (t < 8) tlf[t] = (ids[b * Sn + i0 + t] == 0) ? 1 : 0;
    { int i = t >> 5, d = t & 31; Qs[i * 33 + d] = Q[(b * Sn + i0 + i) * Hn + h * 32 + d]; }
    __syncthreads();
    int tlany = 0;
#pragma unroll
    for (int i = 0; i < 8; ++i) tlany |= tlf[i];
    int ntiles = tlany ? 8 : (((i0 + 7) >> 6) + 1);
    int n = ntiles * 64;

    int iq = t >> 5, jj = t & 31;
    int iglob = i0 + iq;
    int tl_i = tlf[iq];

    // pass 1: scores
    for (int jt = 0; jt < ntiles; ++jt) {
        int j0 = jt * 64;
        __syncthreads();
        for (int f = t; f < 64 * 32; f += 256) {
            int jl = f >> 5, d = f & 31;
            KV[jl * 33 + d] = K[(b * Sn + j0 + jl) * Hn + h * 32 + d];
        }
        __syncthreads();
        int jA = j0 + jj, jB = j0 + jj + 32;
        float sA, sB;
        if (tl_i) { sA = NEGF; sB = NEGF; }
        else {
            float accA = 0.f, accB = 0.f;
#pragma unroll
            for (int d = 0; d < 32; ++d) {
                float q = Qs[iq * 33 + d];
                accA += q * KV[jj * 33 + d];
                accB += q * KV[(jj + 32) * 33 + d];
            }
            if (jA <= iglob) {
                int tv = tmat[(b * Sn + iglob) * Sn + jA];
                sA = (accA + QT[(bh * Sn + iglob) * Tt + tv]) * INV_SQRT_D;
            } else sA = NEGF;
            if (jB <= iglob) {
                int tv = tmat[(b * Sn + iglob) * Sn + jB];
                sB = (accB + QT[(bh * Sn + iglob) * Tt + tv]) * INV_SQRT_D;
            } else sB = NEGF;
        }
        S[iq * 512 + jA] = sA;
        S[iq * 512 + jB] = sB;
    }
    __syncthreads();

    // softmax per row (32-lane groups)
    {
        float m = -INFINITY;
        for (int j = jj; j < n; j += 32) m = fmaxf(m, S[iq * 512 + j]);
        m = red32max(m);
        float sum = 0.f;
        for (int j = jj; j < n; j += 32) {
            float e = expf(S[iq * 512 + j] - m);
            S[iq * 512 + j] = e;
            sum += e;
        }
        sum = red32sum(sum);
        if (jj == 0) invl[iq] = 1.f / sum;
    }

    // pass 2: PV with tV gather (thread = (i, d))
    int d = t & 31;
    float acc = 0.f;
    for (int jt = 0; jt < ntiles; ++jt) {
        int j0 = jt * 64;
        __syncthreads();
        for (int f = t; f < 64 * 32; f += 256) {
            int jl = f >> 5, dd = f & 31;
            KV[jl * 33 + dd] = V[(b * Sn + j0 + jl) * Hn + h * 32 + dd];
        }
        __syncthreads();
        for (int jl = 0; jl < 64; ++jl) {
            int j = j0 + jl;
            float p = S[iq * 512 + j];
            if (p != 0.f) {
                int tv2 = tmat[(b * Sn + iglob) * Sn + j];
                acc += p * (KV[jl * 33 + d] + tVw[tv2 * Hn + h * 32 + d]);
            }
        }
    }
    O[(b * Sn + iglob) * Hn + h * 32 + d] = acc * invl[iq];
}

// ---------------------------------------------------------------------------
// FFN: residual + LN + GEMM1 + gelu + GEMM2 + residual + keep.
// 4 rows per block, 256 threads (split-k = 2).
// ---------------------------------------------------------------------------
__global__ __launch_bounds__(256) void ffn_kernel(
    const int* __restrict__ ids,
    const float* __restrict__ Qn, const float* __restrict__ O,
    const float* __restrict__ flng, const float* __restrict__ flnb,
    const float* __restrict__ w1WT, const float* __restrict__ w1b,
    const float* __restrict__ w2WT, const float* __restrict__ w2b,
    float* __restrict__ vecs, int nb)
{
    int r0 = blockIdx.x * 4, t = threadIdx.x;
    __shared__ float ys[512], h1s[512], parts[512], mv[8];
    {
        int f = t, r = f >> 7, c = f & 127;
        ys[r * 128 + c] = Qn[(r0 + r) * 128 + c] + O[(r0 + r) * 128 + c];
        f = t + 256; r = f >> 7; c = f & 127;
        ys[r * 128 + c] = Qn[(r0 + r) * 128 + c] + O[(r0 + r) * 128 + c];
    }
    __syncthreads();
    int g = t >> 6, l = t & 63;
    float a = ys[g * 128 + l], b2 = ys[g * 128 + 64 + l];
    float mean = red64(a + b2) * (1.f / 128.f);
    float d1 = a - mean, d2 = b2 - mean;
    float var = red64(d1 * d1 + d2 * d2) * (1.f / 128.f);
    if (l == 0) { mv[g * 2] = mean; mv[g * 2 + 1] = rsqrtf(var + EPSF); }
    __syncthreads();
    {
        int f = t, r = f >> 7, c = f & 127;
        ys[r * 128 + c] = (ys[r * 128 + c] - mv[r * 2]) * mv[r * 2 + 1] * flng[nb * 128 + c] + flnb[nb * 128 + c];
        f = t + 256; r = f >> 7; c = f & 127;
        ys[r * 128 + c] = (ys[r * 128 + c] - mv[r * 2]) * mv[r * 2 + 1] * flng[nb * 128 + c] + flnb[nb * 128 + c];
    }
    __syncthreads();
    int h = t & 127, kh = t >> 7;
    float a1[4] = {0.f,0.f,0.f,0.f};
    const float* w1 = w1WT + nb * 16384;
    for (int k = kh * 64; k < kh * 64 + 64; ++k) {
        float w = w1[k * 128 + h];
#pragma unroll
        for (int r = 0; r < 4; ++r) a1[r] += ys[r * 128 + k] * w;
    }
    if (kh) {
#pragma unroll
        for (int r = 0; r < 4; ++r) parts[r * 128 + h] = a1[r];
    }
    __syncthreads();
    if (!kh) {
#pragma unroll
        for (int r = 0; r < 4; ++r) {
            float v2 = a1[r] + parts[r * 128 + h] + w1b[nb * 128 + h];
            h1s[r * 128 + h] = 0.5f * v2 * (1.f + erff(v2 * 0.70710678118654752f));
        }
    }
    __syncthreads();
    float a2[4] = {0.f,0.f,0.f,0.f};
    const float* w2 = w2WT + nb * 16384;
    for (int k = kh * 64; k < kh * 64 + 64; ++k) {
        float w = w2[k * 128 + h];
#pragma unroll
        for (int r = 0; r < 4; ++r) a2[r] += h1s[r * 128 + k] * w;
    }
    if (kh) {
#pragma unroll
        for (int r = 0; r < 4; ++r) parts[r * 128 + h] = a2[r];
    }
    __syncthreads();
    if (!kh) {
#pragma unroll
        for (int r = 0; r < 4; ++r) {
            int row = r0 + r;
            float z = a2[r] + parts[r * 128 + h] + w2b[nb * 128 + h] + ys[r * 128 + h];
            vecs[row * 128 + h] = (ids[row] == 0) ? 0.f : z;
        }
    }
}

// ---------------------------------------------------------------------------
// Final LN
// ---------------------------------------------------------------------------
__global__ __launch_bounds__(256) void final_kernel(
    const float* __restrict__ vecs,
    const float* __restrict__ g2, const float* __restrict__ bta,
    float* __restrict__ out)
{
    int r0 = blockIdx.x * 4, t = threadIdx.x;
    __shared__ float xs[512], mv[8];
    {
        int f = t, r = f >> 7, c = f & 127;
        xs[r * 128 + c] = vecs[(r0 + r) * 128 + c];
        f = t + 256; r = f >> 7; c = f & 127;
        xs[r * 128 + c] = vecs[(r0 + r) * 128 + c];
    }
    __syncthreads();
    int g = t >> 6, l = t & 63;
    float a = xs[g * 128 + l], b2 = xs[g * 128 + 64 + l];
    float mean = red64(a + b2) * (1.f / 128.f);
    float d1 = a - mean, d2 = b2 - mean;
    float var = red64(d1 * d1 + d2 * d2) * (1.f / 128.f);
    if (l == 0) { mv[g * 2] = mean; mv[g * 2 + 1] = rsqrtf(var + EPSF); }
    __syncthreads();
    {
        int f = t, r = f >> 7, c = f & 127;
        out[(r0 + r) * 128 + c] = (xs[r * 128 + c] - mv[r * 2]) * mv[r * 2 + 1] * g2[c] + bta[c];
        f = t + 256; r = f >> 7; c = f & 127;
        out[(r0 + r) * 128 + c] = (xs[r * 128 + c] - mv[r * 2]) * mv[r * 2 + 1] * g2[c] + bta[c];
    }
}

// ---------------------------------------------------------------------------
extern "C" void kernel_launch(void* const* d_in, const int* in_sizes, int n_in,
                              void* d_out, int out_size, void* d_ws, size_t ws_size,
                              hipStream_t stream) {
    const int*   ids   = (const int*)  d_in[0];
    const float* meta  = (const float*)d_in[1];
    const int*   cats  = (const int*)  d_in[2];
    const int*   tmat  = (const int*)  d_in[3];
    const float* itemw = (const float*)d_in[4];
    const float* catw  = (const float*)d_in[5];
    const float* numW  = (const float*)d_in[6];
    const float* numb  = (const float*)d_in[7];
    const float* fusW  = (const float*)d_in[8];
    const float* fusb  = (const float*)d_in[9];
    const float* elng  = (const float*)d_in[10];
    const float* elnb  = (const float*)d_in[11];
    const float* posK  = (const float*)d_in[12];
    const float* posV  = (const float*)d_in[13];
    const float* tKw   = (const float*)d_in[14];
    const float* tVw   = (const float*)d_in[15];
    const float* alng  = (const float*)d_in[16];
    const float* alnb  = (const float*)d_in[17];
    const float* QW    = (const float*)d_in[18];
    const float* Qb    = (const float*)d_in[19];
    const float* KW    = (const float*)d_in[20];
    const float* Kb    = (const float*)d_in[21];
    const float* VW    = (const float*)d_in[22];
    const float* Vb    = (const float*)d_in[23];
    const float* flng  = (const float*)d_in[24];
    const float* flnb  = (const float*)d_in[25];
    const float* w1W   = (const float*)d_in[26];
    const float* w1b   = (const float*)d_in[27];
    const float* w2W   = (const float*)d_in[28];
    const float* w2b   = (const float*)d_in[29];
    const float* llng  = (const float*)d_in[30];
    const float* llnb  = (const float*)d_in[31];
    (void)in_sizes; (void)n_in; (void)out_size; (void)ws_size;

    float* ws = (float*)d_ws;
    float* vecs = ws + OFF_VECS;
    float* Qn   = ws + OFF_QN;
    float* Q    = ws + OFF_Q;
    float* K    = ws + OFF_K;
    float* V    = ws + OFF_V;
    float* O    = ws + OFF_O;
    float* QT   = ws + OFF_QT;
    float* tKT  = ws + OFF_TKT;
    float* fusWT= ws + OFF_FUSWT;
    float* QWT  = ws + OFF_QWT;
    float* KWT  = ws + OFF_KWT;
    float* VWT  = ws + OFF_VWT;
    float* w1WT = ws + OFF_W1WT;
    float* w2WT = ws + OFF_W2WT;
    float* out  = (float*)d_out;

    transpose_all<<<228, 256, 0, stream>>>(fusW, QW, KW, VW, w1W, w2W, tKw, ws);
    embed_kernel<<<ROWS / 4, 256, 0, stream>>>(ids, meta, cats, itemw, catw,
                                               numW, numb, fusWT, fusb, elng,
                                               elnb, vecs);
    for (int nb = 0; nb < NBn; ++nb) {
        qkv_kernel<<<ROWS / 4, 256, 0, stream>>>(vecs, alng, alnb, QWT, Qb,
                                                 KWT, Kb, VWT, Vb, posK, posV,
                                                 Qn, Q, K, V, nb);
        qt_kernel<<<8 * 32, 256, 0, stream>>>(Q, tKT, QT);
        attn_kernel<<<8 * 64, 256, 0, stream>>>(ids, tmat, Q, K, V, tVw, QT, O);
        ffn_kernel<<<ROWS / 4, 256, 0, stream>>>(ids, Qn, O, flng, flnb, w1WT,
                                                 w1b, w2WT, w2b, vecs, nb);
    }
    final_kernel<<<ROWS / 4, 256, 0, stream>>>(vecs, llng, llnb, out);
}

// Round 4
// 432.670 us; speedup vs baseline: 1.2088x; 1.2088x over previous
//
#include <hip/hip_runtime.h>
#include <math.h>

// Problem constants
#define Bn 2
#define Sn 512
#define Hn 128
#define NHn 4
#define Dn 32
#define BAGn 5
#define NMETAn 16
#define ROWS 1024
#define NBn 2
#define Tt 257

#define NEGF (-4294967295.0f)
#define INV_SQRT_D 0.17677669529663687f
#define SQRT_H 11.313708498984761f
#define EPS_EMB 1e-5f
#define EPSF 1e-8f

// workspace float offsets
#define OFF_VECS  0
#define OFF_QN    131072
#define OFF_Q     262144
#define OFF_K     393216
#define OFF_V     524288
#define OFF_O     655360
#define OFF_QT    786432          // 8*512*257 = 1052672 floats
#define OFF_TKT   1839104         // 128*257 = 32896
#define OFF_FUSWT 1872000         // 256*128
#define OFF_QWT   1904768         // 2*16384
#define OFF_KWT   1937536
#define OFF_VWT   1970304
#define OFF_W1WT  2003072
#define OFF_W2WT  2035840

static __device__ __forceinline__ float red64(float v) {
#pragma unroll
    for (int m = 1; m < 64; m <<= 1) v += __shfl_xor(v, m, 64);
    return v;
}
static __device__ __forceinline__ float red64max(float v) {
#pragma unroll
    for (int m = 1; m < 64; m <<= 1) v = fmaxf(v, __shfl_xor(v, m, 64));
    return v;
}
static __device__ __forceinline__ float red32sum(float v) {
#pragma unroll
    for (int m = 1; m < 32; m <<= 1) v += __shfl_xor(v, m, 32);
    return v;
}

// ---------------------------------------------------------------------------
// Transpose all weight matrices into ws (once per call).
// blocks 0..31: fusW [128,256] -> fusWT [256,128]
// blocks 32..191: 10 x [128,128] (QW0,QW1,KW0,KW1,VW0,VW1,w1W0,w1W1,w2W0,w2W1)
// blocks 192..227: tKw [257,128] -> tKT [128,257]
// ---------------------------------------------------------------------------
__global__ __launch_bounds__(256) void transpose_all(
    const float* __restrict__ fusW, const float* __restrict__ QW,
    const float* __restrict__ KW, const float* __restrict__ VW,
    const float* __restrict__ w1W, const float* __restrict__ w2W,
    const float* __restrict__ tKw, float* __restrict__ ws)
{
    int bid = blockIdx.x;
    const float* src; float* dst; int R, C, tile;
    if (bid < 32) { src = fusW; dst = ws + OFF_FUSWT; R = 128; C = 256; tile = bid; }
    else if (bid < 192) {
        int m = (bid - 32) >> 4; tile = (bid - 32) & 15; R = 128; C = 128;
        switch (m) {
            case 0: src = QW;          dst = ws + OFF_QWT;          break;
            case 1: src = QW + 16384;  dst = ws + OFF_QWT + 16384;  break;
            case 2: src = KW;          dst = ws + OFF_KWT;          break;
            case 3: src = KW + 16384;  dst = ws + OFF_KWT + 16384;  break;
            case 4: src = VW;          dst = ws + OFF_VWT;          break;
            case 5: src = VW + 16384;  dst = ws + OFF_VWT + 16384;  break;
            case 6: src = w1W;         dst = ws + OFF_W1WT;         break;
            case 7: src = w1W + 16384; dst = ws + OFF_W1WT + 16384; break;
            case 8: src = w2W;         dst = ws + OFF_W2WT;         break;
            default:src = w2W + 16384; dst = ws + OFF_W2WT + 16384; break;
        }
    } else { src = tKw; dst = ws + OFF_TKT; R = 257; C = 128; tile = bid - 192; }

    int ctiles = C >> 5;
    int rt = tile / ctiles, ct = tile % ctiles;
    int r0 = rt * 32, c0 = ct * 32;
    __shared__ float ts[32][33];
    int c = threadIdx.x & 31, r = threadIdx.x >> 5;
#pragma unroll
    for (int rr = r; rr < 32; rr += 8) {
        int gr = r0 + rr;
        ts[rr][c] = (gr < R) ? src[gr * C + c0 + c] : 0.f;
    }
    __syncthreads();
    int rr2 = threadIdx.x & 31, cb = threadIdx.x >> 5;
#pragma unroll
    for (int cc = cb; cc < 32; cc += 8) {
        int gr = r0 + rr2;
        if (gr < R) dst[(c0 + cc) * R + gr] = ts[rr2][cc];
    }
}

// ---------------------------------------------------------------------------
// Embed: item/cat/num -> fusion GEMM (transposed W) -> LN -> keep.
// 4 rows per block, 256 threads.
// ---------------------------------------------------------------------------
__global__ __launch_bounds__(256) void embed_kernel(
    const int* __restrict__ ids, const float* __restrict__ meta,
    const int* __restrict__ cats,
    const float* __restrict__ item_w, const float* __restrict__ cat_w,
    const float* __restrict__ numW, const float* __restrict__ numb,
    const float* __restrict__ fusWT, const float* __restrict__ fusb,
    const float* __restrict__ lng, const float* __restrict__ lnb,
    float* __restrict__ vecs)
{
    int r0 = blockIdx.x * 4, t = threadIdx.x;
    __shared__ float combs[4 * 256];
    __shared__ float os[4 * 128];
    __shared__ float parts[4 * 128];
    __shared__ float mv[8];
    __shared__ int idl[4];
    if (t < 4) idl[t] = ids[r0 + t];
    __syncthreads();
    {   // item part
        int f = t, r = f >> 7, c = f & 127;
        combs[r * 256 + c] = item_w[idl[r] * Hn + c] * SQRT_H;
        f = t + 256; r = f >> 7; c = f & 127;
        combs[r * 256 + c] = item_w[idl[r] * Hn + c] * SQRT_H;
    }
    {   // num + cat parts: r = t>>6, c = t&63
        int r = t >> 6, c = t & 63;
        float acc = numb[c];
#pragma unroll
        for (int m2 = 0; m2 < NMETAn; ++m2)
            acc += meta[(r0 + r) * NMETAn + m2] * numW[c * NMETAn + m2];
        combs[r * 256 + 128 + c] = acc;
        float ca = 0.f; int cnt = 0;
#pragma unroll
        for (int k2 = 0; k2 < BAGn; ++k2) {
            int cc2 = cats[(r0 + r) * BAGn + k2];
            if (cc2 != 0) { ca += cat_w[cc2 * 64 + c]; cnt++; }
        }
        combs[r * 256 + 192 + c] = ca / (float)(cnt > 0 ? cnt : 1);
    }
    __syncthreads();
    int h = t & 127, kh = t >> 7;
    float acc[4] = {0.f, 0.f, 0.f, 0.f};
    for (int k = kh * 128; k < kh * 128 + 128; ++k) {
        float w = fusWT[k * 128 + h];
#pragma unroll
        for (int r = 0; r < 4; ++r) acc[r] += combs[r * 256 + k] * w;
    }
    if (kh) {
#pragma unroll
        for (int r = 0; r < 4; ++r) parts[r * 128 + h] = acc[r];
    }
    __syncthreads();
    if (!kh) {
#pragma unroll
        for (int r = 0; r < 4; ++r)
            os[r * 128 + h] = acc[r] + parts[r * 128 + h] + fusb[h];
    }
    __syncthreads();
    int g = t >> 6, l = t & 63;
    float a = os[g * 128 + l], b2 = os[g * 128 + 64 + l];
    float mean = red64(a + b2) * (1.f / 128.f);
    float d1 = a - mean, d2 = b2 - mean;
    float var = red64(d1 * d1 + d2 * d2) * (1.f / 128.f);
    if (l == 0) { mv[g * 2] = mean; mv[g * 2 + 1] = rsqrtf(var + EPS_EMB); }
    __syncthreads();
    {
        int f = t, r = f >> 7, c = f & 127;
        float y = (os[r * 128 + c] - mv[r * 2]) * mv[r * 2 + 1] * lng[c] + lnb[c];
        vecs[(r0 + r) * 128 + c] = (idl[r] == 0) ? 0.f : y;
        f = t + 256; r = f >> 7; c = f & 127;
        y = (os[r * 128 + c] - mv[r * 2]) * mv[r * 2 + 1] * lng[c] + lnb[c];
        vecs[(r0 + r) * 128 + c] = (idl[r] == 0) ? 0.f : y;
    }
}

// ---------------------------------------------------------------------------
// QKV: LN -> 3 GEMMs with transposed weights, posK/posV + bias folded.
// 4 rows per block, 256 threads (split-k = 2).
// ---------------------------------------------------------------------------
__global__ __launch_bounds__(256) void qkv_kernel(
    const float* __restrict__ vecs,
    const float* __restrict__ alng, const float* __restrict__ alnb,
    const float* __restrict__ QWT, const float* __restrict__ Qb,
    const float* __restrict__ KWT, const float* __restrict__ Kb,
    const float* __restrict__ VWT, const float* __restrict__ Vb,
    const float* __restrict__ posK, const float* __restrict__ posV,
    float* __restrict__ Qn, float* __restrict__ Q,
    float* __restrict__ K, float* __restrict__ V, int nb)
{
    int r0 = blockIdx.x * 4, t = threadIdx.x;
    __shared__ float xs[512], qs[512], mv[8];
    __shared__ float pq[512], pk[512], pv[512];
    {
        int f = t, r = f >> 7, c = f & 127;
        xs[r * 128 + c] = vecs[(r0 + r) * 128 + c];
        f = t + 256; r = f >> 7; c = f & 127;
        xs[r * 128 + c] = vecs[(r0 + r) * 128 + c];
    }
    __syncthreads();
    int g = t >> 6, l = t & 63;
    float a = xs[g * 128 + l], b2 = xs[g * 128 + 64 + l];
    float mean = red64(a + b2) * (1.f / 128.f);
    float d1 = a - mean, d2 = b2 - mean;
    float var = red64(d1 * d1 + d2 * d2) * (1.f / 128.f);
    if (l == 0) { mv[g * 2] = mean; mv[g * 2 + 1] = rsqrtf(var + EPSF); }
    __syncthreads();
    {
        int f = t, r = f >> 7, c = f & 127;
        float qn = (xs[r * 128 + c] - mv[r * 2]) * mv[r * 2 + 1] * alng[nb * 128 + c] + alnb[nb * 128 + c];
        qs[r * 128 + c] = qn; Qn[(r0 + r) * 128 + c] = qn;
        f = t + 256; r = f >> 7; c = f & 127;
        qn = (xs[r * 128 + c] - mv[r * 2]) * mv[r * 2 + 1] * alng[nb * 128 + c] + alnb[nb * 128 + c];
        qs[r * 128 + c] = qn; Qn[(r0 + r) * 128 + c] = qn;
    }
    __syncthreads();
    int h = t & 127, kh = t >> 7;
    float aq[4] = {0.f,0.f,0.f,0.f}, ak[4] = {0.f,0.f,0.f,0.f}, av[4] = {0.f,0.f,0.f,0.f};
    const float* qwt = QWT + nb * 16384;
    const float* kwt = KWT + nb * 16384;
    const float* vwt = VWT + nb * 16384;
    for (int k = kh * 64; k < kh * 64 + 64; ++k) {
        float wq = qwt[k * 128 + h], wk = kwt[k * 128 + h], wv = vwt[k * 128 + h];
#pragma unroll
        for (int r = 0; r < 4; ++r) {
            float qv = qs[r * 128 + k], xv = xs[r * 128 + k];
            aq[r] += qv * wq; ak[r] += xv * wk; av[r] += xv * wv;
        }
    }
    if (kh) {
#pragma unroll
        for (int r = 0; r < 4; ++r) {
            pq[r * 128 + h] = aq[r]; pk[r * 128 + h] = ak[r]; pv[r * 128 + h] = av[r];
        }
    }
    __syncthreads();
    if (!kh) {
#pragma unroll
        for (int r = 0; r < 4; ++r) {
            int row = r0 + r, s = row & (Sn - 1);
            Q[row * 128 + h] = aq[r] + pq[r * 128 + h] + Qb[nb * 128 + h];
            K[row * 128 + h] = ak[r] + pk[r * 128 + h] + Kb[nb * 128 + h] + posK[s * 128 + h];
            V[row * 128 + h] = av[r] + pv[r * 128 + h] + Vb[nb * 128 + h] + posV[s * 128 + h];
        }
    }
}

// ---------------------------------------------------------------------------
// QT precompute: QT[bh,i,t] = sum_d Q[b,i,h*32+d] * timeK[t, h*32+d]
// block = (bh, 16-i tile); thread = t-column (0..255; thread<16 handles t=256)
// ---------------------------------------------------------------------------
__global__ __launch_bounds__(256) void qt_kernel(
    const float* __restrict__ Q, const float* __restrict__ tKT,
    float* __restrict__ QT)
{
    int blk = blockIdx.x, t = threadIdx.x;
    int bh = blk >> 5, itile = blk & 31, i0 = itile * 16;
    int b = bh >> 2, h = bh & 3;
    __shared__ float Qs[16 * 33];
    {
        int f = t, i = f >> 5, d = f & 31;
        Qs[i * 33 + d] = Q[(b * Sn + i0 + i) * Hn + h * 32 + d];
        f = t + 256; i = f >> 5; d = f & 31;
        Qs[i * 33 + d] = Q[(b * Sn + i0 + i) * Hn + h * 32 + d];
    }
    __syncthreads();
    float acc[16];
#pragma unroll
    for (int i = 0; i < 16; ++i) acc[i] = 0.f;
    for (int d = 0; d < 32; ++d) {
        float w = tKT[(h * 32 + d) * Tt + t];
#pragma unroll
        for (int i = 0; i < 16; ++i) acc[i] += Qs[i * 33 + d] * w;
    }
#pragma unroll
    for (int i = 0; i < 16; ++i)
        QT[(bh * Sn + i0 + i) * Tt + t] = acc[i];
    if (t < 16) {
        int i = t; float a2 = 0.f;
        for (int d = 0; d < 32; ++d)
            a2 += Qs[i * 33 + d] * tKT[(h * 32 + d) * Tt + 256];
        QT[(bh * Sn + i0 + i) * Tt + 256] = a2;
    }
}

// ---------------------------------------------------------------------------
// Attention: one block per (b, h, i); 256 threads; tiny LDS.
// Pass A: parallel QT gathers. Pass B: coalesced q.K via 32-lane groups.
// Softmax. PV with coalesced V/tVw reads.
// ---------------------------------------------------------------------------
__global__ __launch_bounds__(256) void attn_kernel(
    const int* __restrict__ ids, const int* __restrict__ tmat,
    const float* __restrict__ Q, const float* __restrict__ K,
    const float* __restrict__ V, const float* __restrict__ tVw,
    const float* __restrict__ QT, float* __restrict__ O)
{
    int blk = blockIdx.x, t = threadIdx.x;
    int i = blk & (Sn - 1), h = (blk >> 9) & (NHn - 1), b = blk >> 11;
    int bh = b * NHn + h;
    __shared__ float q[Dn];
    __shared__ float S[Sn];
    __shared__ float part[256];
    __shared__ float wred[4], wred2[4];

    if (t < Dn) q[t] = Q[(b * Sn + i) * Hn + h * Dn + t];
    int tl = (ids[b * Sn + i] == 0);
    int n = tl ? Sn : (i + 1);
    const int* trow = tmat + (b * Sn + i) * Sn;
    const float* QTrow = QT + (bh * Sn + i) * Tt;
    __syncthreads();

    // pass A: time-score gathers, fully thread-parallel
    for (int j = t; j < n; j += 256)
        S[j] = tl ? 0.f : QTrow[trow[j]];
    __syncthreads();

    int g = t >> 5, d = t & 31;
    // pass B: add q.K (coalesced: lanes cover d), scale
    if (!tl) {
        for (int j = g; j < n; j += 8) {
            float pp = q[d] * K[(b * Sn + j) * Hn + h * Dn + d];
            pp = red32sum(pp);
            if (d == 0) S[j] = (S[j] + pp) * INV_SQRT_D;
        }
    }
    __syncthreads();

    // softmax over S[0..n)
    float lm = -INFINITY;
    for (int j = t; j < n; j += 256) lm = fmaxf(lm, S[j]);
    lm = red64max(lm);
    if ((t & 63) == 0) wred[t >> 6] = lm;
    __syncthreads();
    float mx = fmaxf(fmaxf(wred[0], wred[1]), fmaxf(wred[2], wred[3]));
    float ls = 0.f;
    for (int j = t; j < n; j += 256) { float e = expf(S[j] - mx); S[j] = e; ls += e; }
    ls = red64(ls);
    if ((t & 63) == 0) wred2[t >> 6] = ls;
    __syncthreads();
    float inv = 1.f / (wred2[0] + wred2[1] + wred2[2] + wred2[3]);

    // PV: 8 j-groups x 32 d, coalesced V/tVw
    float acc = 0.f;
    for (int j = g; j < n; j += 8) {
        float p = S[j];
        int tv = trow[j];
        acc += p * (V[(b * Sn + j) * Hn + h * Dn + d] + tVw[tv * Hn + h * Dn + d]);
    }
    part[t] = acc;
    __syncthreads();
    if (t < Dn) {
        float a = part[t];
#pragma unroll
        for (int g2 = 1; g2 < 8; ++g2) a += part[g2 * 32 + t];
        O[(b * Sn + i) * Hn + h * Dn + t] = a * inv;
    }
}

// ---------------------------------------------------------------------------
// FFN: residual + LN + GEMM1 + gelu + GEMM2 + residual + keep.
// 4 rows per block, 256 threads (split-k = 2). On last block: fused final LN.
// ---------------------------------------------------------------------------
__global__ __launch_bounds__(256) void ffn_kernel(
    const int* __restrict__ ids,
    const float* __restrict__ Qn, const float* __restrict__ O,
    const float* __restrict__ flng, const float* __restrict__ flnb,
    const float* __restrict__ w1WT, const float* __restrict__ w1b,
    const float* __restrict__ w2WT, const float* __restrict__ w2b,
    float* __restrict__ vecs, int nb,
    const float* __restrict__ llng, const float* __restrict__ llnb,
    float* __restrict__ out, int last)
{
    int r0 = blockIdx.x * 4, t = threadIdx.x;
    __shared__ float ys[512], h1s[512], parts[512], mv[8];
    {
        int f = t, r = f >> 7, c = f & 127;
        ys[r * 128 + c] = Qn[(r0 + r) * 128 + c] + O[(r0 + r) * 128 + c];
        f = t + 256; r = f >> 7; c = f & 127;
        ys[r * 128 + c] = Qn[(r0 + r) * 128 + c] + O[(r0 + r) * 128 + c];
    }
    __syncthreads();
    int g = t >> 6, l = t & 63;
    float a = ys[g * 128 + l], b2 = ys[g * 128 + 64 + l];
    float mean = red64(a + b2) * (1.f / 128.f);
    float d1 = a - mean, d2 = b2 - mean;
    float var = red64(d1 * d1 + d2 * d2) * (1.f / 128.f);
    if (l == 0) { mv[g * 2] = mean; mv[g * 2 + 1] = rsqrtf(var + EPSF); }
    __syncthreads();
    {
        int f = t, r = f >> 7, c = f & 127;
        ys[r * 128 + c] = (ys[r * 128 + c] - mv[r * 2]) * mv[r * 2 + 1] * flng[nb * 128 + c] + flnb[nb * 128 + c];
        f = t + 256; r = f >> 7; c = f & 127;
        ys[r * 128 + c] = (ys[r * 128 + c] - mv[r * 2]) * mv[r * 2 + 1] * flng[nb * 128 + c] + flnb[nb * 128 + c];
    }
    __syncthreads();
    int h = t & 127, kh = t >> 7;
    float a1[4] = {0.f,0.f,0.f,0.f};
    const float* w1 = w1WT + nb * 16384;
    for (int k = kh * 64; k < kh * 64 + 64; ++k) {
        float w = w1[k * 128 + h];
#pragma unroll
        for (int r = 0; r < 4; ++r) a1[r] += ys[r * 128 + k] * w;
    }
    if (kh) {
#pragma unroll
        for (int r = 0; r < 4; ++r) parts[r * 128 + h] = a1[r];
    }
    __syncthreads();
    if (!kh) {
#pragma unroll
        for (int r = 0; r < 4; ++r) {
            float v2 = a1[r] + parts[r * 128 + h] + w1b[nb * 128 + h];
            h1s[r * 128 + h] = 0.5f * v2 * (1.f + erff(v2 * 0.70710678118654752f));
        }
    }
    __syncthreads();
    float a2[4] = {0.f,0.f,0.f,0.f};
    const float* w2 = w2WT + nb * 16384;
    for (int k = kh * 64; k < kh * 64 + 64; ++k) {
        float w = w2[k * 128 + h];
#pragma unroll
        for (int r = 0; r < 4; ++r) a2[r] += h1s[r * 128 + k] * w;
    }
    if (kh) {
#pragma unroll
        for (int r = 0; r < 4; ++r) parts[r * 128 + h] = a2[r];
    }
    __syncthreads();
    if (!kh) {
#pragma unroll
        for (int r = 0; r < 4; ++r) {
            int row = r0 + r;
            float z = a2[r] + parts[r * 128 + h] + w2b[nb * 128 + h] + ys[r * 128 + h];
            z = (ids[row] == 0) ? 0.f : z;
            h1s[r * 128 + h] = z;
            vecs[row * 128 + h] = z;
        }
    }
    if (!last) return;
    __syncthreads();
    // fused final LayerNorm -> out
    a = h1s[g * 128 + l]; b2 = h1s[g * 128 + 64 + l];
    mean = red64(a + b2) * (1.f / 128.f);
    d1 = a - mean; d2 = b2 - mean;
    var = red64(d1 * d1 + d2 * d2) * (1.f / 128.f);
    if (l == 0) { mv[g * 2] = mean; mv[g * 2 + 1] = rsqrtf(var + EPSF); }
    __syncthreads();
    {
        int f = t, r = f >> 7, c = f & 127;
        out[(r0 + r) * 128 + c] = (h1s[r * 128 + c] - mv[r * 2]) * mv[r * 2 + 1] * llng[c] + llnb[c];
        f = t + 256; r = f >> 7; c = f & 127;
        out[(r0 + r) * 128 + c] = (h1s[r * 128 + c] - mv[r * 2]) * mv[r * 2 + 1] * llng[c] + llnb[c];
    }
}

// ---------------------------------------------------------------------------
extern "C" void kernel_launch(void* const* d_in, const int* in_sizes, int n_in,
                              void* d_out, int out_size, void* d_ws, size_t ws_size,
                              hipStream_t stream) {
    const int*   ids   = (const int*)  d_in[0];
    const float* meta  = (const float*)d_in[1];
    const int*   cats  = (const int*)  d_in[2];
    const int*   tmat  = (const int*)  d_in[3];
    const float* itemw = (const float*)d_in[4];
    const float* catw  = (const float*)d_in[5];
    const float* numW  = (const float*)d_in[6];
    const float* numb  = (const float*)d_in[7];
    const float* fusW  = (const float*)d_in[8];
    const float* fusb  = (const float*)d_in[9];
    const float* elng  = (const float*)d_in[10];
    const float* elnb  = (const float*)d_in[11];
    const float* posK  = (const float*)d_in[12];
    const float* posV  = (const float*)d_in[13];
    const float* tKw   = (const float*)d_in[14];
    const float* tVw   = (const float*)d_in[15];
    const float* alng  = (const float*)d_in[16];
    const float* alnb  = (const float*)d_in[17];
    const float* QW    = (const float*)d_in[18];
    const float* Qb    = (const float*)d_in[19];
    const float* KW    = (const float*)d_in[20];
    const float* Kb    = (const float*)d_in[21];
    const float* VW    = (const float*)d_in[22];
    const float* Vb    = (const float*)d_in[23];
    const float* flng  = (const float*)d_in[24];
    const float* flnb  = (const float*)d_in[25];
    const float* w1W   = (const float*)d_in[26];
    const float* w1b   = (const float*)d_in[27];
    const float* w2W   = (const float*)d_in[28];
    const float* w2b   = (const float*)d_in[29];
    const float* llng  = (const float*)d_in[30];
    const float* llnb  = (const float*)d_in[31];
    (void)in_sizes; (void)n_in; (void)out_size; (void)ws_size;

    float* ws = (float*)d_ws;
    float* vecs = ws + OFF_VECS;
    float* Qn   = ws + OFF_QN;
    float* Q    = ws + OFF_Q;
    float* K    = ws + OFF_K;
    float* V    = ws + OFF_V;
    float* O    = ws + OFF_O;
    float* QT   = ws + OFF_QT;
    float* tKT  = ws + OFF_TKT;
    float* fusWT= ws + OFF_FUSWT;
    float* QWT  = ws + OFF_QWT;
    float* KWT  = ws + OFF_KWT;
    float* VWT  = ws + OFF_VWT;
    float* w1WT = ws + OFF_W1WT;
    float* w2WT = ws + OFF_W2WT;
    float* out  = (float*)d_out;

    transpose_all<<<228, 256, 0, stream>>>(fusW, QW, KW, VW, w1W, w2W, tKw, ws);
    embed_kernel<<<ROWS / 4, 256, 0, stream>>>(ids, meta, cats, itemw, catw,
                                               numW, numb, fusWT, fusb, elng,
                                               elnb, vecs);
    for (int nb = 0; nb < NBn; ++nb) {
        qkv_kernel<<<ROWS / 4, 256, 0, stream>>>(vecs, alng, alnb, QWT, Qb,
                                                 KWT, Kb, VWT, Vb, posK, posV,
                                                 Qn, Q, K, V, nb);
        qt_kernel<<<8 * 32, 256, 0, stream>>>(Q, tKT, QT);
        attn_kernel<<<Bn * NHn * Sn, 256, 0, stream>>>(ids, tmat, Q, K, V, tVw,
                                                       QT, O);
        ffn_kernel<<<ROWS / 4, 256, 0, stream>>>(ids, Qn, O, flng, flnb, w1WT,
                                                 w1b, w2WT, w2b, vecs, nb,
                                                 llng, llnb, out,
                                                 (nb == NBn - 1) ? 1 : 0);
    }
}

// Round 5
// 363.533 us; speedup vs baseline: 1.4387x; 1.1902x over previous
//
#include <hip/hip_runtime.h>
#include <math.h>

// Problem constants
#define Bn 2
#define Sn 512
#define Hn 128
#define NHn 4
#define Dn 32
#define BAGn 5
#define NMETAn 16
#define ROWS 1024
#define NBn 2
#define Tt 257

#define NEGF (-4294967295.0f)
#define INV_SQRT_D 0.17677669529663687f
#define SQRT_H 11.313708498984761f
#define EPS_EMB 1e-5f
#define EPSF 1e-8f

// workspace float offsets
#define OFF_VECS  0
#define OFF_QN    131072
#define OFF_Q     262144
#define OFF_K     393216
#define OFF_V     524288
#define OFF_O     655360
#define OFF_QT    786432          // 8*512*257 = 1052672 floats
#define OFF_TKT   1839104         // 128*257 = 32896
#define OFF_FUSWT 1872000         // 256*128
#define OFF_QWT   1904768         // 2*16384
#define OFF_KWT   1937536
#define OFF_VWT   1970304
#define OFF_W1WT  2003072
#define OFF_W2WT  2035840

static __device__ __forceinline__ float red64(float v) {
#pragma unroll
    for (int m = 1; m < 64; m <<= 1) v += __shfl_xor(v, m, 64);
    return v;
}
static __device__ __forceinline__ float red64max(float v) {
#pragma unroll
    for (int m = 1; m < 64; m <<= 1) v = fmaxf(v, __shfl_xor(v, m, 64));
    return v;
}

// ---------------------------------------------------------------------------
// Transpose all weight matrices into ws (once per call).
// ---------------------------------------------------------------------------
__global__ __launch_bounds__(256) void transpose_all(
    const float* __restrict__ fusW, const float* __restrict__ QW,
    const float* __restrict__ KW, const float* __restrict__ VW,
    const float* __restrict__ w1W, const float* __restrict__ w2W,
    const float* __restrict__ tKw, float* __restrict__ ws)
{
    int bid = blockIdx.x;
    const float* src; float* dst; int R, C, tile;
    if (bid < 32) { src = fusW; dst = ws + OFF_FUSWT; R = 128; C = 256; tile = bid; }
    else if (bid < 192) {
        int m = (bid - 32) >> 4; tile = (bid - 32) & 15; R = 128; C = 128;
        switch (m) {
            case 0: src = QW;          dst = ws + OFF_QWT;          break;
            case 1: src = QW + 16384;  dst = ws + OFF_QWT + 16384;  break;
            case 2: src = KW;          dst = ws + OFF_KWT;          break;
            case 3: src = KW + 16384;  dst = ws + OFF_KWT + 16384;  break;
            case 4: src = VW;          dst = ws + OFF_VWT;          break;
            case 5: src = VW + 16384;  dst = ws + OFF_VWT + 16384;  break;
            case 6: src = w1W;         dst = ws + OFF_W1WT;         break;
            case 7: src = w1W + 16384; dst = ws + OFF_W1WT + 16384; break;
            case 8: src = w2W;         dst = ws + OFF_W2WT;         break;
            default:src = w2W + 16384; dst = ws + OFF_W2WT + 16384; break;
        }
    } else { src = tKw; dst = ws + OFF_TKT; R = 257; C = 128; tile = bid - 192; }

    int ctiles = C >> 5;
    int rt = tile / ctiles, ct = tile % ctiles;
    int r0 = rt * 32, c0 = ct * 32;
    __shared__ float ts[32][33];
    int c = threadIdx.x & 31, r = threadIdx.x >> 5;
#pragma unroll
    for (int rr = r; rr < 32; rr += 8) {
        int gr = r0 + rr;
        ts[rr][c] = (gr < R) ? src[gr * C + c0 + c] : 0.f;
    }
    __syncthreads();
    int rr2 = threadIdx.x & 31, cb = threadIdx.x >> 5;
#pragma unroll
    for (int cc = cb; cc < 32; cc += 8) {
        int gr = r0 + rr2;
        if (gr < R) dst[(c0 + cc) * R + gr] = ts[rr2][cc];
    }
}

// ---------------------------------------------------------------------------
// Embed
// ---------------------------------------------------------------------------
__global__ __launch_bounds__(256) void embed_kernel(
    const int* __restrict__ ids, const float* __restrict__ meta,
    const int* __restrict__ cats,
    const float* __restrict__ item_w, const float* __restrict__ cat_w,
    const float* __restrict__ numW, const float* __restrict__ numb,
    const float* __restrict__ fusWT, const float* __restrict__ fusb,
    const float* __restrict__ lng, const float* __restrict__ lnb,
    float* __restrict__ vecs)
{
    int r0 = blockIdx.x * 4, t = threadIdx.x;
    __shared__ float combs[4 * 256];
    __shared__ float os[4 * 128];
    __shared__ float parts[4 * 128];
    __shared__ float mv[8];
    __shared__ int idl[4];
    if (t < 4) idl[t] = ids[r0 + t];
    __syncthreads();
    {
        int f = t, r = f >> 7, c = f & 127;
        combs[r * 256 + c] = item_w[idl[r] * Hn + c] * SQRT_H;
        f = t + 256; r = f >> 7; c = f & 127;
        combs[r * 256 + c] = item_w[idl[r] * Hn + c] * SQRT_H;
    }
    {
        int r = t >> 6, c = t & 63;
        float acc = numb[c];
#pragma unroll
        for (int m2 = 0; m2 < NMETAn; ++m2)
            acc += meta[(r0 + r) * NMETAn + m2] * numW[c * NMETAn + m2];
        combs[r * 256 + 128 + c] = acc;
        float ca = 0.f; int cnt = 0;
#pragma unroll
        for (int k2 = 0; k2 < BAGn; ++k2) {
            int cc2 = cats[(r0 + r) * BAGn + k2];
            if (cc2 != 0) { ca += cat_w[cc2 * 64 + c]; cnt++; }
        }
        combs[r * 256 + 192 + c] = ca / (float)(cnt > 0 ? cnt : 1);
    }
    __syncthreads();
    int h = t & 127, kh = t >> 7;
    float acc[4] = {0.f, 0.f, 0.f, 0.f};
    for (int k = kh * 128; k < kh * 128 + 128; ++k) {
        float w = fusWT[k * 128 + h];
#pragma unroll
        for (int r = 0; r < 4; ++r) acc[r] += combs[r * 256 + k] * w;
    }
    if (kh) {
#pragma unroll
        for (int r = 0; r < 4; ++r) parts[r * 128 + h] = acc[r];
    }
    __syncthreads();
    if (!kh) {
#pragma unroll
        for (int r = 0; r < 4; ++r)
            os[r * 128 + h] = acc[r] + parts[r * 128 + h] + fusb[h];
    }
    __syncthreads();
    int g = t >> 6, l = t & 63;
    float a = os[g * 128 + l], b2 = os[g * 128 + 64 + l];
    float mean = red64(a + b2) * (1.f / 128.f);
    float d1 = a - mean, d2 = b2 - mean;
    float var = red64(d1 * d1 + d2 * d2) * (1.f / 128.f);
    if (l == 0) { mv[g * 2] = mean; mv[g * 2 + 1] = rsqrtf(var + EPS_EMB); }
    __syncthreads();
    {
        int f = t, r = f >> 7, c = f & 127;
        float y = (os[r * 128 + c] - mv[r * 2]) * mv[r * 2 + 1] * lng[c] + lnb[c];
        vecs[(r0 + r) * 128 + c] = (idl[r] == 0) ? 0.f : y;
        f = t + 256; r = f >> 7; c = f & 127;
        y = (os[r * 128 + c] - mv[r * 2]) * mv[r * 2 + 1] * lng[c] + lnb[c];
        vecs[(r0 + r) * 128 + c] = (idl[r] == 0) ? 0.f : y;
    }
}

// ---------------------------------------------------------------------------
// QKV
// ---------------------------------------------------------------------------
__global__ __launch_bounds__(256) void qkv_kernel(
    const float* __restrict__ vecs,
    const float* __restrict__ alng, const float* __restrict__ alnb,
    const float* __restrict__ QWT, const float* __restrict__ Qb,
    const float* __restrict__ KWT, const float* __restrict__ Kb,
    const float* __restrict__ VWT, const float* __restrict__ Vb,
    const float* __restrict__ posK, const float* __restrict__ posV,
    float* __restrict__ Qn, float* __restrict__ Q,
    float* __restrict__ K, float* __restrict__ V, int nb)
{
    int r0 = blockIdx.x * 4, t = threadIdx.x;
    __shared__ float xs[512], qs[512], mv[8];
    __shared__ float pq[512], pk[512], pv[512];
    {
        int f = t, r = f >> 7, c = f & 127;
        xs[r * 128 + c] = vecs[(r0 + r) * 128 + c];
        f = t + 256; r = f >> 7; c = f & 127;
        xs[r * 128 + c] = vecs[(r0 + r) * 128 + c];
    }
    __syncthreads();
    int g = t >> 6, l = t & 63;
    float a = xs[g * 128 + l], b2 = xs[g * 128 + 64 + l];
    float mean = red64(a + b2) * (1.f / 128.f);
    float d1 = a - mean, d2 = b2 - mean;
    float var = red64(d1 * d1 + d2 * d2) * (1.f / 128.f);
    if (l == 0) { mv[g * 2] = mean; mv[g * 2 + 1] = rsqrtf(var + EPSF); }
    __syncthreads();
    {
        int f = t, r = f >> 7, c = f & 127;
        float qn = (xs[r * 128 + c] - mv[r * 2]) * mv[r * 2 + 1] * alng[nb * 128 + c] + alnb[nb * 128 + c];
        qs[r * 128 + c] = qn; Qn[(r0 + r) * 128 + c] = qn;
        f = t + 256; r = f >> 7; c = f & 127;
        qn = (xs[r * 128 + c] - mv[r * 2]) * mv[r * 2 + 1] * alng[nb * 128 + c] + alnb[nb * 128 + c];
        qs[r * 128 + c] = qn; Qn[(r0 + r) * 128 + c] = qn;
    }
    __syncthreads();
    int h = t & 127, kh = t >> 7;
    float aq[4] = {0.f,0.f,0.f,0.f}, ak[4] = {0.f,0.f,0.f,0.f}, av[4] = {0.f,0.f,0.f,0.f};
    const float* qwt = QWT + nb * 16384;
    const float* kwt = KWT + nb * 16384;
    const float* vwt = VWT + nb * 16384;
    for (int k = kh * 64; k < kh * 64 + 64; ++k) {
        float wq = qwt[k * 128 + h], wk = kwt[k * 128 + h], wv = vwt[k * 128 + h];
#pragma unroll
        for (int r = 0; r < 4; ++r) {
            float qv = qs[r * 128 + k], xv = xs[r * 128 + k];
            aq[r] += qv * wq; ak[r] += xv * wk; av[r] += xv * wv;
        }
    }
    if (kh) {
#pragma unroll
        for (int r = 0; r < 4; ++r) {
            pq[r * 128 + h] = aq[r]; pk[r * 128 + h] = ak[r]; pv[r * 128 + h] = av[r];
        }
    }
    __syncthreads();
    if (!kh) {
#pragma unroll
        for (int r = 0; r < 4; ++r) {
            int row = r0 + r, s = row & (Sn - 1);
            Q[row * 128 + h] = aq[r] + pq[r * 128 + h] + Qb[nb * 128 + h];
            K[row * 128 + h] = ak[r] + pk[r * 128 + h] + Kb[nb * 128 + h] + posK[s * 128 + h];
            V[row * 128 + h] = av[r] + pv[r * 128 + h] + Vb[nb * 128 + h] + posV[s * 128 + h];
        }
    }
}

// ---------------------------------------------------------------------------
// QT precompute
// ---------------------------------------------------------------------------
__global__ __launch_bounds__(256) void qt_kernel(
    const float* __restrict__ Q, const float* __restrict__ tKT,
    float* __restrict__ QT)
{
    int blk = blockIdx.x, t = threadIdx.x;
    int bh = blk >> 5, itile = blk & 31, i0 = itile * 16;
    int b = bh >> 2, h = bh & 3;
    __shared__ float Qs[16 * 33];
    {
        int f = t, i = f >> 5, d = f & 31;
        Qs[i * 33 + d] = Q[(b * Sn + i0 + i) * Hn + h * 32 + d];
        f = t + 256; i = f >> 5; d = f & 31;
        Qs[i * 33 + d] = Q[(b * Sn + i0 + i) * Hn + h * 32 + d];
    }
    __syncthreads();
    float acc[16];
#pragma unroll
    for (int i = 0; i < 16; ++i) acc[i] = 0.f;
    for (int d = 0; d < 32; ++d) {
        float w = tKT[(h * 32 + d) * Tt + t];
#pragma unroll
        for (int i = 0; i < 16; ++i) acc[i] += Qs[i * 33 + d] * w;
    }
#pragma unroll
    for (int i = 0; i < 16; ++i)
        QT[(bh * Sn + i0 + i) * Tt + t] = acc[i];
    if (t < 16) {
        int i = t; float a2 = 0.f;
        for (int d = 0; d < 32; ++d)
            a2 += Qs[i * 33 + d] * tKT[(h * 32 + d) * Tt + 256];
        QT[(bh * Sn + i0 + i) * Tt + 256] = a2;
    }
}

// ---------------------------------------------------------------------------
// Attention v3: block = (b, h, 4-query tile), 256 threads.
// K/V staged in LDS tiles (shared across 4 queries), QT row in LDS,
// row == wave (no cross-wave reductions), fully parallel PV.
// ---------------------------------------------------------------------------
__global__ __launch_bounds__(256) void attn_kernel(
    const int* __restrict__ ids, const int* __restrict__ tmat,
    const float* __restrict__ Q, const float* __restrict__ K,
    const float* __restrict__ V, const float* __restrict__ tVw,
    const float* __restrict__ QT, float* __restrict__ O)
{
    int blk = blockIdx.x, t = threadIdx.x;
    int bh = blk >> 7, itile = blk & 127, i0 = itile * 4;
    int b = bh >> 2, h = bh & 3;

    __shared__ float Kt[64 * 33];      // K/V tile, 8448 B
    __shared__ float S[4 * 512];       // scores, 8192 B
    __shared__ float QTl[4 * 260];     // QT rows, 4160 B
    __shared__ float ql[4 * 33];       // q rows
    __shared__ float parts[256];
    __shared__ float invl[4];
    __shared__ int tlf[4];

    if (t < 4) tlf[t] = (ids[b * Sn + i0 + t] == 0) ? 1 : 0;
    if (t < 128) {
        int iq = t >> 5, d = t & 31;
        ql[iq * 33 + d] = Q[(b * Sn + i0 + iq) * Hn + h * 32 + d];
    }
#pragma unroll
    for (int iq = 0; iq < 4; ++iq) {
        for (int c = t; c < Tt; c += 256)
            QTl[iq * 260 + c] = QT[(bh * Sn + i0 + iq) * Tt + c];
    }
    __syncthreads();

    int tl_any = tlf[0] | tlf[1] | tlf[2] | tlf[3];
    int ntiles = tl_any ? 8 : ((i0 + 3) >> 6) + 1;
    int n = ntiles * 64;

    int iq = t >> 6;            // row == wave
    int jj = t & 63;
    int i_g = i0 + iq;
    int my_tl = tlf[iq];

    // ---- scores ----
    for (int jt = 0; jt < ntiles; ++jt) {
        int j0 = jt * 64;
        __syncthreads();
        for (int f = t; f < 64 * 32; f += 256) {
            int jl = f >> 5, d = f & 31;
            Kt[jl * 33 + d] = K[(b * Sn + j0 + jl) * Hn + h * 32 + d];
        }
        __syncthreads();
        int j = j0 + jj;
        float sv;
        if (my_tl || j > i_g) sv = NEGF;
        else {
            float acc = 0.f;
#pragma unroll
            for (int d = 0; d < 32; ++d)
                acc += ql[iq * 33 + d] * Kt[jj * 33 + d];
            int tv = tmat[(b * Sn + i_g) * Sn + j];
            sv = (acc + QTl[iq * 260 + tv]) * INV_SQRT_D;
        }
        S[iq * 512 + j] = sv;
    }
    // row == wave: this wave wrote all of S[iq], safe to softmax without barrier

    // ---- softmax (per-wave) ----
    float lm = -INFINITY;
    for (int j = jj; j < n; j += 64) lm = fmaxf(lm, S[iq * 512 + j]);
    lm = red64max(lm);
    float ls = 0.f;
    for (int j = jj; j < n; j += 64) {
        float e = expf(S[iq * 512 + j] - lm);
        S[iq * 512 + j] = e;
        ls += e;
    }
    ls = red64(ls);
    if (jj == 0) invl[iq] = 1.f / ls;

    // ---- PV ----
    int jq = (t >> 5) & 1, d = t & 31;
    const int* trow = tmat + (b * Sn + i_g) * Sn;
    float acc = 0.f;
    for (int jt = 0; jt < ntiles; ++jt) {
        int j0 = jt * 64;
        __syncthreads();
        for (int f = t; f < 64 * 32; f += 256) {
            int jl = f >> 5, dd = f & 31;
            Kt[jl * 33 + dd] = V[(b * Sn + j0 + jl) * Hn + h * 32 + dd];
        }
        __syncthreads();
#pragma unroll 4
        for (int jl = jq * 32; jl < jq * 32 + 32; ++jl) {
            int j = j0 + jl;
            float p = S[iq * 512 + j];
            int tv = trow[j];
            acc += p * (Kt[jl * 33 + d] + tVw[tv * Hn + h * 32 + d]);
        }
    }
    parts[t] = acc;
    __syncthreads();
    if (t < 128) {
        int iq2 = t >> 5, d2 = t & 31;
        float a = parts[iq2 * 64 + d2] + parts[iq2 * 64 + 32 + d2];
        O[(b * Sn + i0 + iq2) * Hn + h * 32 + d2] = a * invl[iq2];
    }
}

// ---------------------------------------------------------------------------
// FFN (+ fused final LN on last block)
// ---------------------------------------------------------------------------
__global__ __launch_bounds__(256) void ffn_kernel(
    const int* __restrict__ ids,
    const float* __restrict__ Qn, const float* __restrict__ O,
    const float* __restrict__ flng, const float* __restrict__ flnb,
    const float* __restrict__ w1WT, const float* __restrict__ w1b,
    const float* __restrict__ w2WT, const float* __restrict__ w2b,
    float* __restrict__ vecs, int nb,
    const float* __restrict__ llng, const float* __restrict__ llnb,
    float* __restrict__ out, int last)
{
    int r0 = blockIdx.x * 4, t = threadIdx.x;
    __shared__ float ys[512], h1s[512], parts[512], mv[8];
    {
        int f = t, r = f >> 7, c = f & 127;
        ys[r * 128 + c] = Qn[(r0 + r) * 128 + c] + O[(r0 + r) * 128 + c];
        f = t + 256; r = f >> 7; c = f & 127;
        ys[r * 128 + c] = Qn[(r0 + r) * 128 + c] + O[(r0 + r) * 128 + c];
    }
    __syncthreads();
    int g = t >> 6, l = t & 63;
    float a = ys[g * 128 + l], b2 = ys[g * 128 + 64 + l];
    float mean = red64(a + b2) * (1.f / 128.f);
    float d1 = a - mean, d2 = b2 - mean;
    float var = red64(d1 * d1 + d2 * d2) * (1.f / 128.f);
    if (l == 0) { mv[g * 2] = mean; mv[g * 2 + 1] = rsqrtf(var + EPSF); }
    __syncthreads();
    {
        int f = t, r = f >> 7, c = f & 127;
        ys[r * 128 + c] = (ys[r * 128 + c] - mv[r * 2]) * mv[r * 2 + 1] * flng[nb * 128 + c] + flnb[nb * 128 + c];
        f = t + 256; r = f >> 7; c = f & 127;
        ys[r * 128 + c] = (ys[r * 128 + c] - mv[r * 2]) * mv[r * 2 + 1] * flng[nb * 128 + c] + flnb[nb * 128 + c];
    }
    __syncthreads();
    int h = t & 127, kh = t >> 7;
    float a1[4] = {0.f,0.f,0.f,0.f};
    const float* w1 = w1WT + nb * 16384;
    for (int k = kh * 64; k < kh * 64 + 64; ++k) {
        float w = w1[k * 128 + h];
#pragma unroll
        for (int r = 0; r < 4; ++r) a1[r] += ys[r * 128 + k] * w;
    }
    if (kh) {
#pragma unroll
        for (int r = 0; r < 4; ++r) parts[r * 128 + h] = a1[r];
    }
    __syncthreads();
    if (!kh) {
#pragma unroll
        for (int r = 0; r < 4; ++r) {
            float v2 = a1[r] + parts[r * 128 + h] + w1b[nb * 128 + h];
            h1s[r * 128 + h] = 0.5f * v2 * (1.f + erff(v2 * 0.70710678118654752f));
        }
    }
    __syncthreads();
    float a2[4] = {0.f,0.f,0.f,0.f};
    const float* w2 = w2WT + nb * 16384;
    for (int k = kh * 64; k < kh * 64 + 64; ++k) {
        float w = w2[k * 128 + h];
#pragma unroll
        for (int r = 0; r < 4; ++r) a2[r] += h1s[r * 128 + k] * w;
    }
    if (kh) {
#pragma unroll
        for (int r = 0; r < 4; ++r) parts[r * 128 + h] = a2[r];
    }
    __syncthreads();
    if (!kh) {
#pragma unroll
        for (int r = 0; r < 4; ++r) {
            int row = r0 + r;
            float z = a2[r] + parts[r * 128 + h] + w2b[nb * 128 + h] + ys[r * 128 + h];
            z = (ids[row] == 0) ? 0.f : z;
            h1s[r * 128 + h] = z;
            vecs[row * 128 + h] = z;
        }
    }
    if (!last) return;
    __syncthreads();
    a = h1s[g * 128 + l]; b2 = h1s[g * 128 + 64 + l];
    mean = red64(a + b2) * (1.f / 128.f);
    d1 = a - mean; d2 = b2 - mean;
    var = red64(d1 * d1 + d2 * d2) * (1.f / 128.f);
    if (l == 0) { mv[g * 2] = mean; mv[g * 2 + 1] = rsqrtf(var + EPSF); }
    __syncthreads();
    {
        int f = t, r = f >> 7, c = f & 127;
        out[(r0 + r) * 128 + c] = (h1s[r * 128 + c] - mv[r * 2]) * mv[r * 2 + 1] * llng[c] + llnb[c];
        f = t + 256; r = f >> 7; c = f & 127;
        out[(r0 + r) * 128 + c] = (h1s[r * 128 + c] - mv[r * 2]) * mv[r * 2 + 1] * llng[c] + llnb[c];
    }
}

// ---------------------------------------------------------------------------
extern "C" void kernel_launch(void* const* d_in, const int* in_sizes, int n_in,
                              void* d_out, int out_size, void* d_ws, size_t ws_size,
                              hipStream_t stream) {
    const int*   ids   = (const int*)  d_in[0];
    const float* meta  = (const float*)d_in[1];
    const int*   cats  = (const int*)  d_in[2];
    const int*   tmat  = (const int*)  d_in[3];
    const float* itemw = (const float*)d_in[4];
    const float* catw  = (const float*)d_in[5];
    const float* numW  = (const float*)d_in[6];
    const float* numb  = (const float*)d_in[7];
    const float* fusW  = (const float*)d_in[8];
    const float* fusb  = (const float*)d_in[9];
    const float* elng  = (const float*)d_in[10];
    const float* elnb  = (const float*)d_in[11];
    const float* posK  = (const float*)d_in[12];
    const float* posV  = (const float*)d_in[13];
    const float* tKw   = (const float*)d_in[14];
    const float* tVw   = (const float*)d_in[15];
    const float* alng  = (const float*)d_in[16];
    const float* alnb  = (const float*)d_in[17];
    const float* QW    = (const float*)d_in[18];
    const float* Qb    = (const float*)d_in[19];
    const float* KW    = (const float*)d_in[20];
    const float* Kb    = (const float*)d_in[21];
    const float* VW    = (const float*)d_in[22];
    const float* Vb    = (const float*)d_in[23];
    const float* flng  = (const float*)d_in[24];
    const float* flnb  = (const float*)d_in[25];
    const float* w1W   = (const float*)d_in[26];
    const float* w1b   = (const float*)d_in[27];
    const float* w2W   = (const float*)d_in[28];
    const float* w2b   = (const float*)d_in[29];
    const float* llng  = (const float*)d_in[30];
    const float* llnb  = (const float*)d_in[31];
    (void)in_sizes; (void)n_in; (void)out_size; (void)ws_size;

    float* ws = (float*)d_ws;
    float* vecs = ws + OFF_VECS;
    float* Qn   = ws + OFF_QN;
    float* Q    = ws + OFF_Q;
    float* K    = ws + OFF_K;
    float* V    = ws + OFF_V;
    float* O    = ws + OFF_O;
    float* QT   = ws + OFF_QT;
    float* tKT  = ws + OFF_TKT;
    float* fusWT= ws + OFF_FUSWT;
    float* QWT  = ws + OFF_QWT;
    float* KWT  = ws + OFF_KWT;
    float* VWT  = ws + OFF_VWT;
    float* w1WT = ws + OFF_W1WT;
    float* w2WT = ws + OFF_W2WT;
    float* out  = (float*)d_out;

    transpose_all<<<228, 256, 0, stream>>>(fusW, QW, KW, VW, w1W, w2W, tKw, ws);
    embed_kernel<<<ROWS / 4, 256, 0, stream>>>(ids, meta, cats, itemw, catw,
                                               numW, numb, fusWT, fusb, elng,
                                               elnb, vecs);
    for (int nb = 0; nb < NBn; ++nb) {
        qkv_kernel<<<ROWS / 4, 256, 0, stream>>>(vecs, alng, alnb, QWT, Qb,
                                                 KWT, Kb, VWT, Vb, posK, posV,
                                                 Qn, Q, K, V, nb);
        qt_kernel<<<8 * 32, 256, 0, stream>>>(Q, tKT, QT);
        attn_kernel<<<8 * 128, 256, 0, stream>>>(ids, tmat, Q, K, V, tVw, QT, O);
        ffn_kernel<<<ROWS / 4, 256, 0, stream>>>(ids, Qn, O, flng, flnb, w1WT,
                                                 w1b, w2WT, w2b, vecs, nb,
                                                 llng, llnb, out,
                                                 (nb == NBn - 1) ? 1 : 0);
    }
}

// Round 6
// 356.613 us; speedup vs baseline: 1.4667x; 1.0194x over previous
//
#include <hip/hip_runtime.h>
#include <math.h>

// Problem constants
#define Bn 2
#define Sn 512
#define Hn 128
#define NHn 4
#define Dn 32
#define BAGn 5
#define NMETAn 16
#define ROWS 1024
#define NBn 2
#define Tt 257

#define NEGF (-4294967295.0f)
#define INV_SQRT_D 0.17677669529663687f
#define SQRT_H 11.313708498984761f
#define EPS_EMB 1e-5f
#define EPSF 1e-8f

// workspace float offsets
#define OFF_VECS  0
#define OFF_QN    131072
#define OFF_Q     262144
#define OFF_K     393216
#define OFF_V     524288
#define OFF_O     655360
#define OFF_FUSWT 786432          // 256*128
#define OFF_QWT   819200          // 2*16384
#define OFF_KWT   851968
#define OFF_VWT   884736
#define OFF_W1WT  917504
#define OFF_W2WT  950272

static __device__ __forceinline__ float red64(float v) {
#pragma unroll
    for (int m = 1; m < 64; m <<= 1) v += __shfl_xor(v, m, 64);
    return v;
}
static __device__ __forceinline__ float red64max(float v) {
#pragma unroll
    for (int m = 1; m < 64; m <<= 1) v = fmaxf(v, __shfl_xor(v, m, 64));
    return v;
}

// ---------------------------------------------------------------------------
// Transpose weight matrices into ws (once per call).
// blocks 0..31: fusW [128,256] -> fusWT [256,128]
// blocks 32..191: 10 x [128,128] (QW0,QW1,KW0,KW1,VW0,VW1,w1W0,w1W1,w2W0,w2W1)
// ---------------------------------------------------------------------------
__global__ __launch_bounds__(256) void transpose_all(
    const float* __restrict__ fusW, const float* __restrict__ QW,
    const float* __restrict__ KW, const float* __restrict__ VW,
    const float* __restrict__ w1W, const float* __restrict__ w2W,
    float* __restrict__ ws)
{
    int bid = blockIdx.x;
    const float* src; float* dst; int C, tile;
    if (bid < 32) { src = fusW; dst = ws + OFF_FUSWT; C = 256; tile = bid; }
    else {
        int m = (bid - 32) >> 4; tile = (bid - 32) & 15; C = 128;
        switch (m) {
            case 0: src = QW;          dst = ws + OFF_QWT;          break;
            case 1: src = QW + 16384;  dst = ws + OFF_QWT + 16384;  break;
            case 2: src = KW;          dst = ws + OFF_KWT;          break;
            case 3: src = KW + 16384;  dst = ws + OFF_KWT + 16384;  break;
            case 4: src = VW;          dst = ws + OFF_VWT;          break;
            case 5: src = VW + 16384;  dst = ws + OFF_VWT + 16384;  break;
            case 6: src = w1W;         dst = ws + OFF_W1WT;         break;
            case 7: src = w1W + 16384; dst = ws + OFF_W1WT + 16384; break;
            case 8: src = w2W;         dst = ws + OFF_W2WT;         break;
            default:src = w2W + 16384; dst = ws + OFF_W2WT + 16384; break;
        }
    }
    int ctiles = C >> 5;
    int rt = tile / ctiles, ct = tile % ctiles;
    int r0 = rt * 32, c0 = ct * 32;
    __shared__ float ts[32][33];
    int c = threadIdx.x & 31, r = threadIdx.x >> 5;
#pragma unroll
    for (int rr = r; rr < 32; rr += 8)
        ts[rr][c] = src[(r0 + rr) * C + c0 + c];
    __syncthreads();
    int rr2 = threadIdx.x & 31, cb = threadIdx.x >> 5;
#pragma unroll
    for (int cc = cb; cc < 32; cc += 8)
        dst[(c0 + cc) * 128 + r0 + rr2] = ts[rr2][cc];
}

// ---------------------------------------------------------------------------
// Embed: 2 rows per block, 512 blocks, 256 threads.
// ---------------------------------------------------------------------------
__global__ __launch_bounds__(256) void embed_kernel(
    const int* __restrict__ ids, const float* __restrict__ meta,
    const int* __restrict__ cats,
    const float* __restrict__ item_w, const float* __restrict__ cat_w,
    const float* __restrict__ numW, const float* __restrict__ numb,
    const float* __restrict__ fusWT, const float* __restrict__ fusb,
    const float* __restrict__ lng, const float* __restrict__ lnb,
    float* __restrict__ vecs)
{
    int r0 = blockIdx.x * 2, t = threadIdx.x;
    __shared__ float combs[2 * 256];
    __shared__ float os[2 * 128];
    __shared__ float parts[2 * 128];
    __shared__ float wsum[8];
    __shared__ int idl[2];
    if (t < 2) idl[t] = ids[r0 + t];
    __syncthreads();
    {
        int r = t >> 7, c = t & 127;
        combs[r * 256 + c] = item_w[idl[r] * Hn + c] * SQRT_H;
    }
    if (t < 128) {
        int r = t >> 6, c = t & 63;
        float acc = numb[c];
#pragma unroll
        for (int m2 = 0; m2 < NMETAn; ++m2)
            acc += meta[(r0 + r) * NMETAn + m2] * numW[c * NMETAn + m2];
        combs[r * 256 + 128 + c] = acc;
    } else {
        int u = t - 128, r = u >> 6, c = u & 63;
        float ca = 0.f; int cnt = 0;
#pragma unroll
        for (int k2 = 0; k2 < BAGn; ++k2) {
            int cc2 = cats[(r0 + r) * BAGn + k2];
            if (cc2 != 0) { ca += cat_w[cc2 * 64 + c]; cnt++; }
        }
        combs[r * 256 + 192 + c] = ca / (float)(cnt > 0 ? cnt : 1);
    }
    __syncthreads();
    int h = t & 127, kh = t >> 7;
    float a0 = 0.f, a1 = 0.f;
    for (int k = kh * 128; k < kh * 128 + 128; ++k) {
        float w = fusWT[k * 128 + h];
        a0 += combs[k] * w;
        a1 += combs[256 + k] * w;
    }
    if (kh) { parts[h] = a0; parts[128 + h] = a1; }
    __syncthreads();
    if (!kh) {
        os[h] = a0 + parts[h] + fusb[h];
        os[128 + h] = a1 + parts[128 + h] + fusb[h];
    }
    __syncthreads();
    int w_ = t >> 6, row = w_ >> 1, l = t & 63, ch = ((w_ & 1) << 6) + l;
    float x = os[row * 128 + ch];
    float s1 = red64(x);
    if (l == 0) wsum[w_] = s1;
    __syncthreads();
    float mean = (wsum[row * 2] + wsum[row * 2 + 1]) * (1.f / 128.f);
    float dlt = x - mean;
    float s2 = red64(dlt * dlt);
    if (l == 0) wsum[4 + w_] = s2;
    __syncthreads();
    float rstd = rsqrtf((wsum[4 + row * 2] + wsum[4 + row * 2 + 1]) * (1.f / 128.f) + EPS_EMB);
    float y = dlt * rstd * lng[ch] + lnb[ch];
    vecs[(r0 + row) * 128 + ch] = (idl[row] == 0) ? 0.f : y;
}

// ---------------------------------------------------------------------------
// QKV: 2 rows per block, 512 blocks, split-k=2.
// ---------------------------------------------------------------------------
__global__ __launch_bounds__(256) void qkv_kernel(
    const float* __restrict__ vecs,
    const float* __restrict__ alng, const float* __restrict__ alnb,
    const float* __restrict__ QWT, const float* __restrict__ Qb,
    const float* __restrict__ KWT, const float* __restrict__ Kb,
    const float* __restrict__ VWT, const float* __restrict__ Vb,
    const float* __restrict__ posK, const float* __restrict__ posV,
    float* __restrict__ Qn, float* __restrict__ Q,
    float* __restrict__ K, float* __restrict__ V, int nb)
{
    int r0 = blockIdx.x * 2, t = threadIdx.x;
    __shared__ float xs[256], qs[256], wsum[8];
    __shared__ float pq[256], pk[256], pv[256];
    xs[t] = vecs[r0 * 128 + t];
    __syncthreads();
    int w_ = t >> 6, row = w_ >> 1, l = t & 63, ch = ((w_ & 1) << 6) + l;
    float x = xs[row * 128 + ch];
    float s1 = red64(x);
    if (l == 0) wsum[w_] = s1;
    __syncthreads();
    float mean = (wsum[row * 2] + wsum[row * 2 + 1]) * (1.f / 128.f);
    float dlt = x - mean;
    float s2 = red64(dlt * dlt);
    if (l == 0) wsum[4 + w_] = s2;
    __syncthreads();
    float rstd = rsqrtf((wsum[4 + row * 2] + wsum[4 + row * 2 + 1]) * (1.f / 128.f) + EPSF);
    float qn = dlt * rstd * alng[nb * 128 + ch] + alnb[nb * 128 + ch];
    qs[row * 128 + ch] = qn;
    Qn[(r0 + row) * 128 + ch] = qn;
    __syncthreads();
    int h = t & 127, kh = t >> 7;
    float aq0 = 0, aq1 = 0, ak0 = 0, ak1 = 0, av0 = 0, av1 = 0;
    const float* qwt = QWT + nb * 16384;
    const float* kwt = KWT + nb * 16384;
    const float* vwt = VWT + nb * 16384;
    for (int k = kh * 64; k < kh * 64 + 64; ++k) {
        float wq = qwt[k * 128 + h], wk = kwt[k * 128 + h], wv = vwt[k * 128 + h];
        float q0 = qs[k], q1 = qs[128 + k], x0 = xs[k], x1 = xs[128 + k];
        aq0 += q0 * wq; aq1 += q1 * wq;
        ak0 += x0 * wk; ak1 += x1 * wk;
        av0 += x0 * wv; av1 += x1 * wv;
    }
    if (kh) {
        pq[h] = aq0; pq[128 + h] = aq1;
        pk[h] = ak0; pk[128 + h] = ak1;
        pv[h] = av0; pv[128 + h] = av1;
    }
    __syncthreads();
    if (!kh) {
        int s0 = r0 & (Sn - 1), s1_ = (r0 + 1) & (Sn - 1);
        Q[r0 * 128 + h]       = aq0 + pq[h]       + Qb[nb * 128 + h];
        Q[(r0 + 1) * 128 + h] = aq1 + pq[128 + h] + Qb[nb * 128 + h];
        K[r0 * 128 + h]       = ak0 + pk[h]       + Kb[nb * 128 + h] + posK[s0 * 128 + h];
        K[(r0 + 1) * 128 + h] = ak1 + pk[128 + h] + Kb[nb * 128 + h] + posK[s1_ * 128 + h];
        V[r0 * 128 + h]       = av0 + pv[h]       + Vb[nb * 128 + h] + posV[s0 * 128 + h];
        V[(r0 + 1) * 128 + h] = av1 + pv[128 + h] + Vb[nb * 128 + h] + posV[s1_ * 128 + h];
    }
}

// ---------------------------------------------------------------------------
// Attention: block = (b,h, strided 4-query set {idx, idx+128, idx+256, idx+384})
// -> uniform work per block. Fused per-block QT compute (no QT tensor).
// ---------------------------------------------------------------------------
__global__ __launch_bounds__(256) void attn_kernel(
    const int* __restrict__ ids, const int* __restrict__ tmat,
    const float* __restrict__ Q, const float* __restrict__ K,
    const float* __restrict__ V,
    const float* __restrict__ tKw, const float* __restrict__ tVw,
    float* __restrict__ O)
{
    int blk = blockIdx.x, t = threadIdx.x;
    int bh = blk >> 7, idx = blk & 127;
    int b = bh >> 2, h = bh & 3;

    __shared__ float Kt[64 * 33];
    __shared__ float S[4 * 512];
    __shared__ float QTl[4 * 260];
    __shared__ float ql[4 * 33];
    __shared__ float parts[256];
    __shared__ float invl[4];
    __shared__ int tlf[4];

    if (t < 4) tlf[t] = (ids[b * Sn + idx + 128 * t] == 0) ? 1 : 0;
    if (t < 128) {
        int q_ = t >> 5, d = t & 31;
        ql[q_ * 33 + d] = Q[(b * Sn + idx + 128 * q_) * Hn + h * 32 + d];
    }
    __syncthreads();

    // fused QT: thread tt computes Q_i . timeK[tt] for the 4 queries
    for (int tt = t; tt < Tt; tt += 256) {
        const float4* tk4 = (const float4*)(tKw + tt * Hn + h * 32);
        float a0 = 0.f, a1 = 0.f, a2 = 0.f, a3 = 0.f;
#pragma unroll
        for (int dv = 0; dv < 8; ++dv) {
            float4 w4 = tk4[dv];
            int d = dv * 4;
            a0 += ql[d] * w4.x + ql[d + 1] * w4.y + ql[d + 2] * w4.z + ql[d + 3] * w4.w;
            a1 += ql[33 + d] * w4.x + ql[33 + d + 1] * w4.y + ql[33 + d + 2] * w4.z + ql[33 + d + 3] * w4.w;
            a2 += ql[66 + d] * w4.x + ql[66 + d + 1] * w4.y + ql[66 + d + 2] * w4.z + ql[66 + d + 3] * w4.w;
            a3 += ql[99 + d] * w4.x + ql[99 + d + 1] * w4.y + ql[99 + d + 2] * w4.z + ql[99 + d + 3] * w4.w;
        }
        QTl[tt] = a0; QTl[260 + tt] = a1; QTl[520 + tt] = a2; QTl[780 + tt] = a3;
    }

    int tl_any = tlf[0] | tlf[1] | tlf[2] | tlf[3];
    int ntiles = tl_any ? 8 : ((idx + 384) >> 6) + 1;

    int iq = t >> 6, jj = t & 63;
    int i_g = idx + 128 * iq;
    int my_tl = tlf[iq];
    const int* trow = tmat + (b * Sn + i_g) * Sn;

    // ---- scores ----
    for (int jt = 0; jt < ntiles; ++jt) {
        int j0 = jt * 64;
        __syncthreads();
        for (int f = t; f < 64 * 8; f += 256) {
            int jl = f >> 3, dv = f & 7;
            float4 w4 = *(const float4*)(K + (b * Sn + j0 + jl) * Hn + h * 32 + dv * 4);
            float* kd = &Kt[jl * 33 + dv * 4];
            kd[0] = w4.x; kd[1] = w4.y; kd[2] = w4.z; kd[3] = w4.w;
        }
        __syncthreads();
        int j = j0 + jj;
        if (my_tl) {
            S[iq * 512 + j] = NEGF;
        } else if (j0 <= i_g) {
            float sv;
            if (j <= i_g) {
                float acc = 0.f;
#pragma unroll
                for (int d = 0; d < 32; ++d)
                    acc += ql[iq * 33 + d] * Kt[jj * 33 + d];
                sv = (acc + QTl[iq * 260 + trow[j]]) * INV_SQRT_D;
            } else sv = NEGF;
            S[iq * 512 + j] = sv;
        }
    }

    // ---- softmax over full staged range of this query (NEGs -> 0) ----
    int n_sm = my_tl ? Sn : (((i_g >> 6) + 1) << 6);
    float lm = -INFINITY;
    for (int j = jj; j < n_sm; j += 64) lm = fmaxf(lm, S[iq * 512 + j]);
    lm = red64max(lm);
    float ls = 0.f;
    for (int j = jj; j < n_sm; j += 64) {
        float e = expf(S[iq * 512 + j] - lm);
        S[iq * 512 + j] = e;
        ls += e;
    }
    ls = red64(ls);
    if (jj == 0) invl[iq] = 1.f / ls;

    // ---- PV ----
    int jq = (t >> 5) & 1, d = t & 31;
    float acc = 0.f;
    for (int jt = 0; jt < ntiles; ++jt) {
        int j0 = jt * 64;
        __syncthreads();
        for (int f = t; f < 64 * 8; f += 256) {
            int jl = f >> 3, dv = f & 7;
            float4 w4 = *(const float4*)(V + (b * Sn + j0 + jl) * Hn + h * 32 + dv * 4);
            float* kd = &Kt[jl * 33 + dv * 4];
            kd[0] = w4.x; kd[1] = w4.y; kd[2] = w4.z; kd[3] = w4.w;
        }
        __syncthreads();
        if (my_tl || j0 <= i_g) {
#pragma unroll 4
            for (int jl = jq * 32; jl < jq * 32 + 32; ++jl) {
                int j = j0 + jl;
                float p = S[iq * 512 + j];
                acc += p * (Kt[jl * 33 + d] + tVw[trow[j] * Hn + h * 32 + d]);
            }
        }
    }
    parts[t] = acc;
    __syncthreads();
    if (t < 128) {
        int iq2 = t >> 5, d2 = t & 31;
        float a = parts[iq2 * 64 + d2] + parts[iq2 * 64 + 32 + d2];
        O[(b * Sn + idx + 128 * iq2) * Hn + h * 32 + d2] = a * invl[iq2];
    }
}

// ---------------------------------------------------------------------------
// FFN: 2 rows per block, 512 blocks (+ fused final LN when last).
// ---------------------------------------------------------------------------
__global__ __launch_bounds__(256) void ffn_kernel(
    const int* __restrict__ ids,
    const float* __restrict__ Qn, const float* __restrict__ O,
    const float* __restrict__ flng, const float* __restrict__ flnb,
    const float* __restrict__ w1WT, const float* __restrict__ w1b,
    const float* __restrict__ w2WT, const float* __restrict__ w2b,
    float* __restrict__ vecs, int nb,
    const float* __restrict__ llng, const float* __restrict__ llnb,
    float* __restrict__ out, int last)
{
    int r0 = blockIdx.x * 2, t = threadIdx.x;
    __shared__ float ys[256], h1s[256], parts[256], wsum[8];
    ys[t] = Qn[r0 * 128 + t] + O[r0 * 128 + t];
    __syncthreads();
    int w_ = t >> 6, row = w_ >> 1, l = t & 63, ch = ((w_ & 1) << 6) + l;
    float x = ys[row * 128 + ch];
    float s1 = red64(x);
    if (l == 0) wsum[w_] = s1;
    __syncthreads();
    float mean = (wsum[row * 2] + wsum[row * 2 + 1]) * (1.f / 128.f);
    float dlt = x - mean;
    float s2 = red64(dlt * dlt);
    if (l == 0) wsum[4 + w_] = s2;
    __syncthreads();
    float rstd = rsqrtf((wsum[4 + row * 2] + wsum[4 + row * 2 + 1]) * (1.f / 128.f) + EPSF);
    float yv = dlt * rstd * flng[nb * 128 + ch] + flnb[nb * 128 + ch];
    __syncthreads();
    ys[row * 128 + ch] = yv;
    __syncthreads();

    int h = t & 127, kh = t >> 7;
    const float* w1 = w1WT + nb * 16384;
    float a10 = 0.f, a11 = 0.f;
    for (int k = kh * 64; k < kh * 64 + 64; ++k) {
        float w = w1[k * 128 + h];
        a10 += ys[k] * w;
        a11 += ys[128 + k] * w;
    }
    if (kh) { parts[h] = a10; parts[128 + h] = a11; }
    __syncthreads();
    if (!kh) {
        float v0 = a10 + parts[h] + w1b[nb * 128 + h];
        float v1 = a11 + parts[128 + h] + w1b[nb * 128 + h];
        h1s[h] = 0.5f * v0 * (1.f + erff(v0 * 0.70710678118654752f));
        h1s[128 + h] = 0.5f * v1 * (1.f + erff(v1 * 0.70710678118654752f));
    }
    __syncthreads();
    const float* w2 = w2WT + nb * 16384;
    float a20 = 0.f, a21 = 0.f;
    for (int k = kh * 64; k < kh * 64 + 64; ++k) {
        float w = w2[k * 128 + h];
        a20 += h1s[k] * w;
        a21 += h1s[128 + k] * w;
    }
    __syncthreads();
    if (kh) { parts[h] = a20; parts[128 + h] = a21; }
    __syncthreads();
    if (!kh) {
        float z0 = a20 + parts[h] + w2b[nb * 128 + h] + ys[h];
        float z1 = a21 + parts[128 + h] + w2b[nb * 128 + h] + ys[128 + h];
        z0 = (ids[r0] == 0) ? 0.f : z0;
        z1 = (ids[r0 + 1] == 0) ? 0.f : z1;
        h1s[h] = z0; h1s[128 + h] = z1;
        vecs[r0 * 128 + h] = z0;
        vecs[(r0 + 1) * 128 + h] = z1;
    }
    if (!last) return;
    __syncthreads();
    // fused final LN
    x = h1s[row * 128 + ch];
    s1 = red64(x);
    if (l == 0) wsum[w_] = s1;
    __syncthreads();
    mean = (wsum[row * 2] + wsum[row * 2 + 1]) * (1.f / 128.f);
    dlt = x - mean;
    s2 = red64(dlt * dlt);
    if (l == 0) wsum[4 + w_] = s2;
    __syncthreads();
    rstd = rsqrtf((wsum[4 + row * 2] + wsum[4 + row * 2 + 1]) * (1.f / 128.f) + EPSF);
    out[(r0 + row) * 128 + ch] = dlt * rstd * llng[ch] + llnb[ch];
}

// ---------------------------------------------------------------------------
extern "C" void kernel_launch(void* const* d_in, const int* in_sizes, int n_in,
                              void* d_out, int out_size, void* d_ws, size_t ws_size,
                              hipStream_t stream) {
    const int*   ids   = (const int*)  d_in[0];
    const float* meta  = (const float*)d_in[1];
    const int*   cats  = (const int*)  d_in[2];
    const int*   tmat  = (const int*)  d_in[3];
    const float* itemw = (const float*)d_in[4];
    const float* catw  = (const float*)d_in[5];
    const float* numW  = (const float*)d_in[6];
    const float* numb  = (const float*)d_in[7];
    const float* fusW  = (const float*)d_in[8];
    const float* fusb  = (const float*)d_in[9];
    const float* elng  = (const float*)d_in[10];
    const float* elnb  = (const float*)d_in[11];
    const float* posK  = (const float*)d_in[12];
    const float* posV  = (const float*)d_in[13];
    const float* tKw   = (const float*)d_in[14];
    const float* tVw   = (const float*)d_in[15];
    const float* alng  = (const float*)d_in[16];
    const float* alnb  = (const float*)d_in[17];
    const float* QW    = (const float*)d_in[18];
    const float* Qb    = (const float*)d_in[19];
    const float* KW    = (const float*)d_in[20];
    const float* Kb    = (const float*)d_in[21];
    const float* VW    = (const float*)d_in[22];
    const float* Vb    = (const float*)d_in[23];
    const float* flng  = (const float*)d_in[24];
    const float* flnb  = (const float*)d_in[25];
    const float* w1W   = (const float*)d_in[26];
    const float* w1b   = (const float*)d_in[27];
    const float* w2W   = (const float*)d_in[28];
    const float* w2b   = (const float*)d_in[29];
    const float* llng  = (const float*)d_in[30];
    const float* llnb  = (const float*)d_in[31];
    (void)in_sizes; (void)n_in; (void)out_size; (void)ws_size;

    float* ws = (float*)d_ws;
    float* vecs = ws + OFF_VECS;
    float* Qn   = ws + OFF_QN;
    float* Q    = ws + OFF_Q;
    float* K    = ws + OFF_K;
    float* V    = ws + OFF_V;
    float* O    = ws + OFF_O;
    float* fusWT= ws + OFF_FUSWT;
    float* QWT  = ws + OFF_QWT;
    float* KWT  = ws + OFF_KWT;
    float* VWT  = ws + OFF_VWT;
    float* w1WT = ws + OFF_W1WT;
    float* w2WT = ws + OFF_W2WT;
    float* out  = (float*)d_out;

    transpose_all<<<192, 256, 0, stream>>>(fusW, QW, KW, VW, w1W, w2W, ws);
    embed_kernel<<<ROWS / 2, 256, 0, stream>>>(ids, meta, cats, itemw, catw,
                                               numW, numb, fusWT, fusb, elng,
                                               elnb, vecs);
    for (int nb = 0; nb < NBn; ++nb) {
        qkv_kernel<<<ROWS / 2, 256, 0, stream>>>(vecs, alng, alnb, QWT, Qb,
                                                 KWT, Kb, VWT, Vb, posK, posV,
                                                 Qn, Q, K, V, nb);
        attn_kernel<<<8 * 128, 256, 0, stream>>>(ids, tmat, Q, K, V, tKw, tVw, O);
        ffn_kernel<<<ROWS / 2, 256, 0, stream>>>(ids, Qn, O, flng, flnb, w1WT,
                                                 w1b, w2WT, w2b, vecs, nb,
                                                 llng, llnb, out,
                                                 (nb == NBn - 1) ? 1 : 0);
    }
}